// Round 1
// baseline (3694.458 us; speedup 1.0000x reference)
//
#include <hip/hip_runtime.h>
#include <hip/hip_bf16.h>
#include <math.h>

#define Bc   2
#define Nc   10000
#define Ec   100000
#define Hc   128
#define DINc 8
#define DBc  16
#define NBc  3
#define Lc   2
#define K1c  257
#define TE   32

typedef float v4 __attribute__((ext_vector_type(4)));

__device__ __forceinline__ float silu_f(float x) { return x / (1.f + expf(-x)); }

// ---------------- small utility kernels ----------------

__global__ void zero4_kernel(float* __restrict__ p, int n4) {
  int i = blockIdx.x * blockDim.x + threadIdx.x;
  if (i < n4) ((v4*)p)[i] = (v4)(0.f);
}

__global__ void count_deg_kernel(float* __restrict__ deg, const int* __restrict__ edge_dst) {
  int i = blockIdx.x * blockDim.x + threadIdx.x;
  if (i < NBc * Ec) {
    int k = i / Ec;
    atomicAdd(&deg[k * Nc + edge_dst[i]], 1.0f);
  }
}

__global__ void recip_deg_kernel(float* __restrict__ deg) {
  int i = blockIdx.x * blockDim.x + threadIdx.x;
  if (i < NBc * Nc) deg[i] = 1.0f / fmaxf(deg[i], 1.0f);
}

__global__ void init_h_kernel(float* __restrict__ h, const float* __restrict__ bfeat,
                              const float* __restrict__ x, const float* __restrict__ Win,
                              const float* __restrict__ b_in, const int* __restrict__ ent) {
  int g = blockIdx.x * blockDim.x + threadIdx.x;
  if (g >= Bc * Nc * Hc) return;
  int j = g & (Hc - 1);
  int bn = g >> 7;
  int n = bn % Nc;
  int b = bn / Nc;
  float acc = b_in[j];
#pragma unroll
  for (int i = 0; i < DBc; ++i) acc = fmaf(bfeat[n * DBc + i], Win[i * Hc + j], acc);
  if (n == ent[b]) {
#pragma unroll
    for (int i = 0; i < DINc; ++i) acc = fmaf(x[b * DINc + i], Win[(DBc + i) * Hc + j], acc);
  }
  h[g] = acc;
}

__global__ void init_p_kernel(float* __restrict__ p, const float* __restrict__ bp) {
  int i = blockIdx.x * blockDim.x + threadIdx.x;
  if (i < Bc * Nc * 3) p[i] = bp[i % (Nc * 3)];
}

__global__ void copy_kernel(float* __restrict__ dst, const float* __restrict__ src, int n) {
  int i = blockIdx.x * blockDim.x + threadIdx.x;
  if (i < n) dst[i] = src[i];
}

// ---------------- fused edge MLP kernel ----------------
// grid: (B*E/TE, NB). 256 threads. Each block: 32 edge-instances.
// thread (er = tid>>5 in 0..7, jr = tid&31): owns edges er*4..er*4+3, cols jr*4..jr*4+3.

__global__ __launch_bounds__(256, 1)
void edge_kernel(const float* __restrict__ h, const float* __restrict__ p,
                 float* __restrict__ m_sum, float* __restrict__ p_new,
                 const float* __restrict__ deg_inv,
                 const int* __restrict__ edge_src, const int* __restrict__ edge_dst,
                 const float* __restrict__ msg_W1, const float* __restrict__ msg_b1,
                 const float* __restrict__ msg_W2, const float* __restrict__ msg_b2,
                 const float* __restrict__ pos_W1, const float* __restrict__ pos_b1,
                 const float* __restrict__ pos_W2, const float* __restrict__ pos_b2,
                 int l) {
  const int k  = blockIdx.y;
  const int lk = l * NBc + k;
  const int tid = threadIdx.x;
  const int jr = tid & 31;
  const int er = tid >> 5;
  const int j0 = jr << 2;

  __shared__ __align__(16) float Hd[TE][Hc + 4];   // gathered h[dst]; later m1
  __shared__ __align__(16) float Hs[TE][Hc + 4];   // gathered h[src]; later m2
  __shared__ __align__(16) float Wt[32][Hc];       // weight K-tile
  __shared__ __align__(16) float Wlast[Hc];        // W1 row 256 (d2 row)
  __shared__ int ssi[TE], sdi[TE], sb[TE];
  __shared__ float srel[TE][3], sd2[TE], sdinv[TE], scoef[TE];

  const float* W1 = msg_W1 + (size_t)lk * K1c * Hc;

  if (tid < TE) {
    int g = blockIdx.x * TE + tid;            // B*E divisible by TE
    int b = g / Ec;
    int e = g - b * Ec;
    int si = edge_src[k * Ec + e];
    int di = edge_dst[k * Ec + e];
    ssi[tid] = si; sdi[tid] = di; sb[tid] = b;
    const float* pd = &p[((size_t)(b * Nc + di)) * 3];
    const float* ps = &p[((size_t)(b * Nc + si)) * 3];
    float rx = pd[0] - ps[0], ry = pd[1] - ps[1], rz = pd[2] - ps[2];
    srel[tid][0] = rx; srel[tid][1] = ry; srel[tid][2] = rz;
    sd2[tid] = rx * rx + ry * ry + rz * rz;
    sdinv[tid] = deg_inv[k * Nc + di];
  }
  if (tid >= 64 && tid < 96) {
    int t = tid - 64;
    *(v4*)&Wlast[t * 4] = *(const v4*)&W1[256 * Hc + t * 4];
  }
  __syncthreads();

  // gather h rows (coalesced within each row)
#pragma unroll
  for (int pass = 0; pass < 4; ++pass) {
    int i = pass * 8 + er;
    int c4 = jr << 2;
    int b = sb[i];
    *(v4*)&Hd[i][c4] = *(const v4*)&h[((size_t)(b * Nc + sdi[i])) * Hc + c4];
    *(v4*)&Hs[i][c4] = *(const v4*)&h[((size_t)(b * Nc + ssi[i])) * Hc + c4];
  }

  float acc[4][4];

  // ---- GEMM1: [32,257] x [257,128] (d2 row handled separately) ----
  {
    v4 bb = *(const v4*)&msg_b1[lk * Hc + j0];
#pragma unroll
    for (int i = 0; i < 4; ++i)
#pragma unroll
      for (int c = 0; c < 4; ++c) acc[i][c] = bb[c];
  }
  for (int kt = 0; kt < 8; ++kt) {
    __syncthreads();
#pragma unroll
    for (int q = 0; q < 4; ++q) {
      int idx = tid + q * 256;
      int row = idx >> 5;
      int col = (idx & 31) << 2;
      *(v4*)&Wt[row][col] = *(const v4*)&W1[(size_t)(kt * 32 + row) * Hc + col];
    }
    __syncthreads();
    const float (*A)[Hc + 4] = (kt < 4) ? Hd : Hs;
    const int kb = (kt & 3) * 32;
#pragma unroll
    for (int kk = 0; kk < 8; ++kk) {
      v4 a4[4], w4[4];
#pragma unroll
      for (int i = 0; i < 4; ++i) a4[i] = *(const v4*)&A[er * 4 + i][kb + kk * 4];
#pragma unroll
      for (int r = 0; r < 4; ++r) w4[r] = *(const v4*)&Wt[kk * 4 + r][j0];
#pragma unroll
      for (int i = 0; i < 4; ++i)
#pragma unroll
        for (int r = 0; r < 4; ++r)
#pragma unroll
          for (int c = 0; c < 4; ++c)
            acc[i][c] = fmaf(a4[i][r], w4[r][c], acc[i][c]);
    }
  }
  __syncthreads();
  {
    v4 wl = *(const v4*)&Wlast[j0];
#pragma unroll
    for (int i = 0; i < 4; ++i) {
      float d2v = sd2[er * 4 + i];
#pragma unroll
      for (int c = 0; c < 4; ++c)
        Hd[er * 4 + i][j0 + c] = silu_f(fmaf(d2v, wl[c], acc[i][c]));   // m1 -> Hd
    }
  }

  // ---- GEMM2: m2 = silu(m1 @ W2 + b2) ----
  const float* W2 = msg_W2 + (size_t)lk * Hc * Hc;
  {
    v4 bb = *(const v4*)&msg_b2[lk * Hc + j0];
#pragma unroll
    for (int i = 0; i < 4; ++i)
#pragma unroll
      for (int c = 0; c < 4; ++c) acc[i][c] = bb[c];
  }
  for (int kt = 0; kt < 4; ++kt) {
    __syncthreads();
#pragma unroll
    for (int q = 0; q < 4; ++q) {
      int idx = tid + q * 256;
      int row = idx >> 5;
      int col = (idx & 31) << 2;
      *(v4*)&Wt[row][col] = *(const v4*)&W2[(size_t)(kt * 32 + row) * Hc + col];
    }
    __syncthreads();
    const int kb = kt * 32;
#pragma unroll
    for (int kk = 0; kk < 8; ++kk) {
      v4 a4[4], w4[4];
#pragma unroll
      for (int i = 0; i < 4; ++i) a4[i] = *(const v4*)&Hd[er * 4 + i][kb + kk * 4];
#pragma unroll
      for (int r = 0; r < 4; ++r) w4[r] = *(const v4*)&Wt[kk * 4 + r][j0];
#pragma unroll
      for (int i = 0; i < 4; ++i)
#pragma unroll
        for (int r = 0; r < 4; ++r)
#pragma unroll
          for (int c = 0; c < 4; ++c)
            acc[i][c] = fmaf(a4[i][r], w4[r][c], acc[i][c]);
    }
  }
  __syncthreads();
  float m2r[4][4];
#pragma unroll
  for (int i = 0; i < 4; ++i)
#pragma unroll
    for (int c = 0; c < 4; ++c) {
      m2r[i][c] = silu_f(acc[i][c]);
      Hs[er * 4 + i][j0 + c] = m2r[i][c];                                // m2 -> Hs
    }

  // ---- GEMM3: q = silu(m2 @ posW1 + posb1); coef = q . posW2 + posb2 ----
  const float* PW1 = pos_W1 + (size_t)lk * Hc * Hc;
  {
    v4 bb = *(const v4*)&pos_b1[lk * Hc + j0];
#pragma unroll
    for (int i = 0; i < 4; ++i)
#pragma unroll
      for (int c = 0; c < 4; ++c) acc[i][c] = bb[c];
  }
  for (int kt = 0; kt < 4; ++kt) {
    __syncthreads();
#pragma unroll
    for (int q = 0; q < 4; ++q) {
      int idx = tid + q * 256;
      int row = idx >> 5;
      int col = (idx & 31) << 2;
      *(v4*)&Wt[row][col] = *(const v4*)&PW1[(size_t)(kt * 32 + row) * Hc + col];
    }
    __syncthreads();
    const int kb = kt * 32;
#pragma unroll
    for (int kk = 0; kk < 8; ++kk) {
      v4 a4[4], w4[4];
#pragma unroll
      for (int i = 0; i < 4; ++i) a4[i] = *(const v4*)&Hs[er * 4 + i][kb + kk * 4];
#pragma unroll
      for (int r = 0; r < 4; ++r) w4[r] = *(const v4*)&Wt[kk * 4 + r][j0];
#pragma unroll
      for (int i = 0; i < 4; ++i)
#pragma unroll
        for (int r = 0; r < 4; ++r)
#pragma unroll
          for (int c = 0; c < 4; ++c)
            acc[i][c] = fmaf(a4[i][r], w4[r][c], acc[i][c]);
    }
  }
  {
    v4 pw2 = *(const v4*)&pos_W2[lk * Hc + j0];
    float pb2s = pos_b2[lk];
    float part[4];
#pragma unroll
    for (int i = 0; i < 4; ++i) {
      float s = 0.f;
#pragma unroll
      for (int c = 0; c < 4; ++c) s = fmaf(silu_f(acc[i][c]), pw2[c], s);
      part[i] = s;
    }
#pragma unroll
    for (int off = 16; off > 0; off >>= 1)
#pragma unroll
      for (int i = 0; i < 4; ++i) part[i] += __shfl_xor(part[i], off);
    if (jr == 0) {
#pragma unroll
      for (int i = 0; i < 4; ++i) scoef[er * 4 + i] = part[i] + pb2s;
    }
  }
  __syncthreads();

  // ---- scatter m_sum (per-edge scale by 1/deg[dst] == reference's post-scatter divide) ----
#pragma unroll
  for (int i = 0; i < 4; ++i) {
    int ei = er * 4 + i;
    float dv = sdinv[ei];
    float* dstp = &m_sum[((size_t)(sb[ei] * Nc + sdi[ei])) * Hc + j0];
#pragma unroll
    for (int c = 0; c < 4; ++c) atomicAdd(&dstp[c], m2r[i][c] * dv);
  }
  // ---- scatter p_new ----
  if (tid < TE) {
    float cf = scoef[tid] * sdinv[tid];
    float* pp = &p_new[((size_t)(sb[tid] * Nc + sdi[tid])) * 3];
    atomicAdd(&pp[0], srel[tid][0] * cf);
    atomicAdd(&pp[1], srel[tid][1] * cf);
    atomicAdd(&pp[2], srel[tid][2] * cf);
  }
}

// ---------------- node update kernel ----------------
// h = h + silu([h|m_sum] @ uW1 + ub1) @ uW2 + ub2.  32 rows/block over B*N.

__global__ __launch_bounds__(256, 1)
void update_kernel(float* __restrict__ h, const float* __restrict__ m_sum,
                   const float* __restrict__ uW1, const float* __restrict__ ub1,
                   const float* __restrict__ uW2, const float* __restrict__ ub2,
                   int l) {
  const int tid = threadIdx.x;
  const int jr = tid & 31;
  const int er = tid >> 5;
  const int j0 = jr << 2;
  const int row0 = blockIdx.x * TE;

  __shared__ __align__(16) float Hd[TE][Hc + 4];   // h rows; later u1
  __shared__ __align__(16) float Hs[TE][Hc + 4];   // m_sum rows
  __shared__ __align__(16) float Wt[32][Hc];

  const float* W1 = uW1 + (size_t)l * 2 * Hc * Hc;
  const float* W2 = uW2 + (size_t)l * Hc * Hc;

#pragma unroll
  for (int pass = 0; pass < 4; ++pass) {
    int i = pass * 8 + er;
    int c4 = jr << 2;
    size_t r = (size_t)(row0 + i) * Hc + c4;
    *(v4*)&Hd[i][c4] = *(const v4*)&h[r];
    *(v4*)&Hs[i][c4] = *(const v4*)&m_sum[r];
  }

  float acc[4][4];
  {
    v4 bb = *(const v4*)&ub1[l * Hc + j0];
#pragma unroll
    for (int i = 0; i < 4; ++i)
#pragma unroll
      for (int c = 0; c < 4; ++c) acc[i][c] = bb[c];
  }
  for (int kt = 0; kt < 8; ++kt) {
    __syncthreads();
#pragma unroll
    for (int q = 0; q < 4; ++q) {
      int idx = tid + q * 256;
      int row = idx >> 5;
      int col = (idx & 31) << 2;
      *(v4*)&Wt[row][col] = *(const v4*)&W1[(size_t)(kt * 32 + row) * Hc + col];
    }
    __syncthreads();
    const float (*A)[Hc + 4] = (kt < 4) ? Hd : Hs;
    const int kb = (kt & 3) * 32;
#pragma unroll
    for (int kk = 0; kk < 8; ++kk) {
      v4 a4[4], w4[4];
#pragma unroll
      for (int i = 0; i < 4; ++i) a4[i] = *(const v4*)&A[er * 4 + i][kb + kk * 4];
#pragma unroll
      for (int r = 0; r < 4; ++r) w4[r] = *(const v4*)&Wt[kk * 4 + r][j0];
#pragma unroll
      for (int i = 0; i < 4; ++i)
#pragma unroll
        for (int r = 0; r < 4; ++r)
#pragma unroll
          for (int c = 0; c < 4; ++c)
            acc[i][c] = fmaf(a4[i][r], w4[r][c], acc[i][c]);
    }
  }
  __syncthreads();
#pragma unroll
  for (int i = 0; i < 4; ++i)
#pragma unroll
    for (int c = 0; c < 4; ++c)
      Hd[er * 4 + i][j0 + c] = silu_f(acc[i][c]);                        // u1 -> Hd

  {
    v4 bb = *(const v4*)&ub2[l * Hc + j0];
#pragma unroll
    for (int i = 0; i < 4; ++i)
#pragma unroll
      for (int c = 0; c < 4; ++c) acc[i][c] = bb[c];
  }
  for (int kt = 0; kt < 4; ++kt) {
    __syncthreads();
#pragma unroll
    for (int q = 0; q < 4; ++q) {
      int idx = tid + q * 256;
      int row = idx >> 5;
      int col = (idx & 31) << 2;
      *(v4*)&Wt[row][col] = *(const v4*)&W2[(size_t)(kt * 32 + row) * Hc + col];
    }
    __syncthreads();
    const int kb = kt * 32;
#pragma unroll
    for (int kk = 0; kk < 8; ++kk) {
      v4 a4[4], w4[4];
#pragma unroll
      for (int i = 0; i < 4; ++i) a4[i] = *(const v4*)&Hd[er * 4 + i][kb + kk * 4];
#pragma unroll
      for (int r = 0; r < 4; ++r) w4[r] = *(const v4*)&Wt[kk * 4 + r][j0];
#pragma unroll
      for (int i = 0; i < 4; ++i)
#pragma unroll
        for (int r = 0; r < 4; ++r)
#pragma unroll
          for (int c = 0; c < 4; ++c)
            acc[i][c] = fmaf(a4[i][r], w4[r][c], acc[i][c]);
    }
  }
  // h += (u1 @ W2 + b2)  — rows exclusive to this block, no atomics needed
#pragma unroll
  for (int i = 0; i < 4; ++i) {
    float* hp = &h[(size_t)(row0 + er * 4 + i) * Hc + j0];
    v4 old = *(const v4*)hp;
    v4 nv;
#pragma unroll
    for (int c = 0; c < 4; ++c) nv[c] = old[c] + acc[i][c];
    *(v4*)hp = nv;
  }
}

// ---------------- readout ----------------

__global__ void readout_kernel(const float* __restrict__ h, const int* __restrict__ ent,
                               const float* __restrict__ oW1, const float* __restrict__ ob1,
                               const float* __restrict__ oW2, const float* __restrict__ ob2,
                               float* __restrict__ out) {
  __shared__ float tb[Bc][Hc];
  int tid = threadIdx.x;
  int b = tid >> 7, j = tid & 127;
  const float* e = &h[((size_t)(b * Nc + ent[b])) * Hc];
  float a = ob1[j];
#pragma unroll 4
  for (int i = 0; i < Hc; ++i) a = fmaf(e[i], oW1[i * Hc + j], a);
  tb[b][j] = silu_f(a);
  __syncthreads();
  if (tid < Bc) {
    float s = ob2[0];
    for (int i = 0; i < Hc; ++i) s = fmaf(tb[tid][i], oW2[i], s);
    out[tid] = s;
  }
}

// ---------------- host launcher ----------------

extern "C" void kernel_launch(void* const* d_in, const int* in_sizes, int n_in,
                              void* d_out, int out_size, void* d_ws, size_t ws_size,
                              hipStream_t stream) {
  const float* x    = (const float*)d_in[0];
  const float* bfe  = (const float*)d_in[1];
  const float* bp   = (const float*)d_in[2];
  const float* Win  = (const float*)d_in[3];
  const float* b_in = (const float*)d_in[4];
  const float* mW1  = (const float*)d_in[5];
  const float* mb1  = (const float*)d_in[6];
  const float* mW2  = (const float*)d_in[7];
  const float* mb2  = (const float*)d_in[8];
  const float* pW1  = (const float*)d_in[9];
  const float* pb1  = (const float*)d_in[10];
  const float* pW2  = (const float*)d_in[11];
  const float* pb2  = (const float*)d_in[12];
  const float* uW1  = (const float*)d_in[13];
  const float* ub1  = (const float*)d_in[14];
  const float* uW2  = (const float*)d_in[15];
  const float* ub2  = (const float*)d_in[16];
  const float* oW1  = (const float*)d_in[17];
  const float* ob1  = (const float*)d_in[18];
  const float* oW2  = (const float*)d_in[19];
  const float* ob2  = (const float*)d_in[20];
  const int* ent    = (const int*)d_in[21];
  const int* esrc   = (const int*)d_in[22];
  const int* edst   = (const int*)d_in[23];

  float* w = (float*)d_ws;
  float* h    = w;  w += (size_t)Bc * Nc * Hc;    // 2.56M
  float* msum = w;  w += (size_t)Bc * Nc * Hc;    // 2.56M
  float* pa   = w;  w += (size_t)Bc * Nc * 3;     // 60K
  float* pb_  = w;  w += (size_t)Bc * Nc * 3;     // 60K
  float* deg  = w;  w += (size_t)NBc * Nc;        // 30K   (total ~21 MB)

  const int ndeg = NBc * Nc;
  zero4_kernel<<<dim3((ndeg / 4 + 255) / 256), dim3(256), 0, stream>>>(deg, ndeg / 4);
  count_deg_kernel<<<dim3((NBc * Ec + 255) / 256), dim3(256), 0, stream>>>(deg, edst);
  recip_deg_kernel<<<dim3((ndeg + 255) / 256), dim3(256), 0, stream>>>(deg);

  init_h_kernel<<<dim3((Bc * Nc * Hc + 255) / 256), dim3(256), 0, stream>>>(h, bfe, x, Win, b_in, ent);
  init_p_kernel<<<dim3((Bc * Nc * 3 + 255) / 256), dim3(256), 0, stream>>>(pa, bp);

  float* pcur = pa;
  float* pnew = pb_;
  const int nmh = Bc * Nc * Hc;
  for (int l = 0; l < Lc; ++l) {
    zero4_kernel<<<dim3((nmh / 4 + 255) / 256), dim3(256), 0, stream>>>(msum, nmh / 4);
    copy_kernel<<<dim3((Bc * Nc * 3 + 255) / 256), dim3(256), 0, stream>>>(pnew, pcur, Bc * Nc * 3);
    edge_kernel<<<dim3(Bc * Ec / TE, NBc), dim3(256), 0, stream>>>(
        h, pcur, msum, pnew, deg, esrc, edst,
        mW1, mb1, mW2, mb2, pW1, pb1, pW2, pb2, l);
    update_kernel<<<dim3(Bc * Nc / TE), dim3(256), 0, stream>>>(h, msum, uW1, ub1, uW2, ub2, l);
    float* t = pcur; pcur = pnew; pnew = t;
  }
  readout_kernel<<<dim3(1), dim3(256), 0, stream>>>(h, ent, oW1, ob1, oW2, ob2, (float*)d_out);
}

// Round 2
// 903.627 us; speedup vs baseline: 4.0885x; 4.0885x over previous
//
#include <hip/hip_runtime.h>
#include <hip/hip_bf16.h>
#include <math.h>

#define Bc   2
#define Nc   10000
#define Ec   100000
#define Hc   128
#define DINc 8
#define DBc  16
#define NBc  3
#define Lc   2

typedef float v4 __attribute__((ext_vector_type(4)));
typedef float f32x16 __attribute__((ext_vector_type(16)));
typedef _Float16 h8 __attribute__((ext_vector_type(8)));
typedef _Float16 h4 __attribute__((ext_vector_type(4)));

__device__ __forceinline__ float silu_f(float x) { return x / (1.f + __expf(-x)); }

// ---------------- small utility kernels ----------------

__global__ void zero4_kernel(float* __restrict__ p, int n4) {
  int i = blockIdx.x * blockDim.x + threadIdx.x;
  if (i < n4) ((v4*)p)[i] = (v4)(0.f);
}

__global__ void count_deg_kernel(float* __restrict__ deg, const int* __restrict__ edge_dst) {
  int i = blockIdx.x * blockDim.x + threadIdx.x;
  if (i < NBc * Ec) {
    int k = i / Ec;
    atomicAdd(&deg[k * Nc + edge_dst[i]], 1.0f);
  }
}

__global__ void recip_deg_kernel(float* __restrict__ deg) {
  int i = blockIdx.x * blockDim.x + threadIdx.x;
  if (i < NBc * Nc) deg[i] = 1.0f / fmaxf(deg[i], 1.0f);
}

__global__ void init_h_kernel(float* __restrict__ h, const float* __restrict__ bfeat,
                              const float* __restrict__ x, const float* __restrict__ Win,
                              const float* __restrict__ b_in, const int* __restrict__ ent) {
  int g = blockIdx.x * blockDim.x + threadIdx.x;
  if (g >= Bc * Nc * Hc) return;
  int j = g & (Hc - 1);
  int bn = g >> 7;
  int n = bn % Nc;
  int b = bn / Nc;
  float acc = b_in[j];
#pragma unroll
  for (int i = 0; i < DBc; ++i) acc = fmaf(bfeat[n * DBc + i], Win[i * Hc + j], acc);
  if (n == ent[b]) {
#pragma unroll
    for (int i = 0; i < DINc; ++i) acc = fmaf(x[b * DINc + i], Win[(DBc + i) * Hc + j], acc);
  }
  h[g] = acc;
}

__global__ void init_p_kernel(float* __restrict__ p, const float* __restrict__ bp) {
  int i = blockIdx.x * blockDim.x + threadIdx.x;
  if (i < Bc * Nc * 3) p[i] = bp[i % (Nc * 3)];
}

__global__ void copy_kernel(float* __restrict__ dst, const float* __restrict__ src, int n) {
  int i = blockIdx.x * blockDim.x + threadIdx.x;
  if (i < n) dst[i] = src[i];
}

// ---------------- weight -> f16 MFMA-fragment-order conversion ----------------
// dst[(((mat*4 + wave)*nchunk + t)*64 + lane)*8 + j]
//   = (f16) src[mat*srcStride + (t*16 + (lane>>5)*8 + j)*128 + wave*32 + (lane&31)]
__global__ void conv_frag_kernel(_Float16* __restrict__ dst, const float* __restrict__ src,
                                 int nchunk, int total, long srcStride) {
  int g = blockIdx.x * blockDim.x + threadIdx.x;
  if (g >= total) return;
  int j = g & 7;
  int lane = (g >> 3) & 63;
  int q = g >> 9;
  int t = q % nchunk;
  int q2 = q / nchunk;
  int wave = q2 & 3;
  int mat = q2 >> 2;
  int kk = t * 16 + (lane >> 5) * 8 + j;
  int col = wave * 32 + (lane & 31);
  dst[g] = (_Float16)src[(size_t)mat * srcStride + (size_t)kk * Hc + col];
}

// ---------------- fused edge MLP kernel (f16 MFMA) ----------------
// grid (B*E/32, NB), 256 threads = 4 waves. Block: 32 edge-instances x 128 cols.
// Wave w owns cols w*32..w*32+31. C-frag mapping (32x32x16):
//   col = lane&31 (+wave base), row = (reg&3) + 8*(reg>>2) + 4*(lane>>5).

__global__ __launch_bounds__(256, 4)
void edge_mfma_kernel(const float* __restrict__ h, const float* __restrict__ p,
                      float* __restrict__ m_sum, float* __restrict__ p_new,
                      const float* __restrict__ deg_inv,
                      const int* __restrict__ esrc, const int* __restrict__ edst,
                      const _Float16* __restrict__ W1f, const _Float16* __restrict__ W2f,
                      const _Float16* __restrict__ P1f,
                      const float* __restrict__ mW1, const float* __restrict__ mb1,
                      const float* __restrict__ mb2, const float* __restrict__ pb1,
                      const float* __restrict__ pW2, const float* __restrict__ pb2,
                      int l) {
  const int k = blockIdx.y, lk = l * NBc + k;
  const int tid = threadIdx.x;
  const int wave = tid >> 6, lane = tid & 63;
  const int lrow = lane & 31, lhalf = lane >> 5;
  const int colg = (wave << 5) + lrow;

  // Abuf: [32 rows][256 f16], 512B row stride, XOR-swizzled (byte ^= (row&7)<<4).
  // GEMM1 A = [h_dst | h_src]; reused after GEMM2 for m2 (bytes 0..255 of each row).
  __shared__ __align__(16) _Float16 Abuf[32 * 256];
  // Mbuf: [32 rows][128 f16], 256B row stride, same swizzle. Holds m1.
  __shared__ __align__(16) _Float16 Mbuf[32 * 128];
  __shared__ int shd[32], shs[32], spo[32];
  __shared__ float sd2[32], sdinv[32], srel[32][3], scoef[32];

  if (tid < 32) {
    int g = blockIdx.x * 32 + tid;
    int b = g / Ec, e = g - b * Ec;
    int si = esrc[k * Ec + e], di = edst[k * Ec + e];
    int nd = b * Nc + di, ns = b * Nc + si;
    const float* pd = &p[(size_t)nd * 3];
    const float* ps = &p[(size_t)ns * 3];
    float rx = pd[0] - ps[0], ry = pd[1] - ps[1], rz = pd[2] - ps[2];
    srel[tid][0] = rx; srel[tid][1] = ry; srel[tid][2] = rz;
    sd2[tid] = rx * rx + ry * ry + rz * rz;
    sdinv[tid] = deg_inv[k * Nc + di];
    shd[tid] = nd * Hc; shs[tid] = ns * Hc; spo[tid] = nd * 3;
    scoef[tid] = 0.f;
  }
  __syncthreads();

  // gather h rows -> f16 into Abuf
  {
    const int er = tid >> 5, jr = tid & 31;
    char* ab = (char*)Abuf;
#pragma unroll
    for (int pass = 0; pass < 4; ++pass) {
      int i = pass * 8 + er;
      int sw = (i & 7) << 4;
      v4 dv = *(const v4*)&h[shd[i] + (jr << 2)];
      v4 sv = *(const v4*)&h[shs[i] + (jr << 2)];
      h4 dh, sh2;
#pragma unroll
      for (int c = 0; c < 4; ++c) { dh[c] = (_Float16)dv[c]; sh2[c] = (_Float16)sv[c]; }
      *(h4*)(ab + (i << 9) + ((jr << 3) ^ sw)) = dh;
      *(h4*)(ab + (i << 9) + ((256 + (jr << 3)) ^ sw)) = sh2;
    }
  }
  __syncthreads();

  const int swz = (lrow & 7) << 4;
  const char* abc = (const char*)Abuf;
  const char* mbc = (const char*)Mbuf;

  // ---- GEMM1: [32,256]x[256,128] f16 MFMA (d2 row + bias in fp32 epilogue) ----
  f32x16 acc;
#pragma unroll
  for (int r = 0; r < 16; ++r) acc[r] = 0.f;
#pragma unroll
  for (int t = 0; t < 16; ++t) {
    h8 a = *(const h8*)(abc + (lrow << 9) + ((((t << 5) + (lhalf << 4))) ^ swz));
    h8 b = *(const h8*)&W1f[((((size_t)lk * 4 + wave) * 16 + t) << 9) + (lane << 3)];
    acc = __builtin_amdgcn_mfma_f32_32x32x16_f16(a, b, acc, 0, 0, 0);
  }
  {
    float wl = mW1[((size_t)lk * 257 + 256) * Hc + colg];   // d2 row of W1, fp32
    float b1 = mb1[lk * Hc + colg];
    char* mb = (char*)Mbuf;
#pragma unroll
    for (int r = 0; r < 16; ++r) {
      int row = (r & 3) + ((r >> 2) << 3) + (lhalf << 2);
      float v = silu_f(acc[r] + sd2[row] * wl + b1);
      *(_Float16*)(mb + (row << 8) + (((colg << 1)) ^ ((row & 7) << 4))) = (_Float16)v;
    }
  }
  __syncthreads();

  // ---- GEMM2: m2 = silu(m1 @ W2 + b2) ----
  f32x16 acc2;
#pragma unroll
  for (int r = 0; r < 16; ++r) acc2[r] = 0.f;
#pragma unroll
  for (int t = 0; t < 8; ++t) {
    h8 a = *(const h8*)(mbc + (lrow << 8) + ((((t << 5) + (lhalf << 4))) ^ swz));
    h8 b = *(const h8*)&W2f[((((size_t)lk * 4 + wave) * 8 + t) << 9) + (lane << 3)];
    acc2 = __builtin_amdgcn_mfma_f32_32x32x16_f16(a, b, acc2, 0, 0, 0);
  }
  {
    float b2 = mb2[lk * Hc + colg];
    char* ab = (char*)Abuf;
#pragma unroll
    for (int r = 0; r < 16; ++r) {
      int row = (r & 3) + ((r >> 2) << 3) + (lhalf << 2);
      float v = silu_f(acc2[r] + b2);
      atomicAdd(&m_sum[shd[row] + colg], v * sdinv[row]);   // fp32 scatter
      *(_Float16*)(ab + (row << 9) + (((colg << 1)) ^ ((row & 7) << 4))) = (_Float16)v;
    }
  }
  __syncthreads();

  // ---- GEMM3: q = silu(m2 @ posW1 + posb1); coef = q . posW2 + posb2 ----
  f32x16 acc3;
#pragma unroll
  for (int r = 0; r < 16; ++r) acc3[r] = 0.f;
#pragma unroll
  for (int t = 0; t < 8; ++t) {
    h8 a = *(const h8*)(abc + (lrow << 9) + ((((t << 5) + (lhalf << 4))) ^ swz));
    h8 b = *(const h8*)&P1f[((((size_t)lk * 4 + wave) * 8 + t) << 9) + (lane << 3)];
    acc3 = __builtin_amdgcn_mfma_f32_32x32x16_f16(a, b, acc3, 0, 0, 0);
  }
  {
    float pb1v = pb1[lk * Hc + colg];
    float pw2v = pW2[lk * Hc + colg];
#pragma unroll
    for (int r = 0; r < 16; ++r) {
      float q = silu_f(acc3[r] + pb1v) * pw2v;
#pragma unroll
      for (int off = 16; off >= 1; off >>= 1) q += __shfl_xor(q, off);
      if (lrow == 0) {
        int row = (r & 3) + ((r >> 2) << 3) + (lhalf << 2);
        atomicAdd(&scoef[row], q);   // LDS atomic, 32 adds/wave
      }
    }
  }
  __syncthreads();
  if (tid < 32) {
    float cf = (scoef[tid] + pb2[lk]) * sdinv[tid];
    float* pp = &p_new[spo[tid]];
    atomicAdd(&pp[0], srel[tid][0] * cf);
    atomicAdd(&pp[1], srel[tid][1] * cf);
    atomicAdd(&pp[2], srel[tid][2] * cf);
  }
}

// ---------------- node update kernel (f16 MFMA) ----------------
// h += silu([h|m_sum] @ uW1 + ub1) @ uW2 + ub2. 32 rows/block, rows exclusive.

__global__ __launch_bounds__(256, 4)
void update_mfma_kernel(float* __restrict__ h, const float* __restrict__ m_sum,
                        const _Float16* __restrict__ U1f, const _Float16* __restrict__ U2f,
                        const float* __restrict__ ub1, const float* __restrict__ ub2, int l) {
  const int tid = threadIdx.x;
  const int wave = tid >> 6, lane = tid & 63;
  const int lrow = lane & 31, lhalf = lane >> 5;
  const int colg = (wave << 5) + lrow;
  const int row0 = blockIdx.x << 5;

  __shared__ __align__(16) _Float16 Abuf[32 * 256];
  __shared__ __align__(16) _Float16 Mbuf[32 * 128];

  {
    const int er = tid >> 5, jr = tid & 31;
    char* ab = (char*)Abuf;
#pragma unroll
    for (int pass = 0; pass < 4; ++pass) {
      int i = pass * 8 + er;
      int sw = (i & 7) << 4;
      size_t base = (size_t)(row0 + i) * Hc + (jr << 2);
      v4 hv = *(const v4*)&h[base];
      v4 mv = *(const v4*)&m_sum[base];
      h4 hh, mh;
#pragma unroll
      for (int c = 0; c < 4; ++c) { hh[c] = (_Float16)hv[c]; mh[c] = (_Float16)mv[c]; }
      *(h4*)(ab + (i << 9) + ((jr << 3) ^ sw)) = hh;
      *(h4*)(ab + (i << 9) + ((256 + (jr << 3)) ^ sw)) = mh;
    }
  }
  __syncthreads();

  const int swz = (lrow & 7) << 4;
  const char* abc = (const char*)Abuf;
  const char* mbc = (const char*)Mbuf;

  f32x16 acc;
#pragma unroll
  for (int r = 0; r < 16; ++r) acc[r] = 0.f;
#pragma unroll
  for (int t = 0; t < 16; ++t) {
    h8 a = *(const h8*)(abc + (lrow << 9) + ((((t << 5) + (lhalf << 4))) ^ swz));
    h8 b = *(const h8*)&U1f[((((size_t)l * 4 + wave) * 16 + t) << 9) + (lane << 3)];
    acc = __builtin_amdgcn_mfma_f32_32x32x16_f16(a, b, acc, 0, 0, 0);
  }
  {
    float b1 = ub1[l * Hc + colg];
    char* mb = (char*)Mbuf;
#pragma unroll
    for (int r = 0; r < 16; ++r) {
      int row = (r & 3) + ((r >> 2) << 3) + (lhalf << 2);
      float v = silu_f(acc[r] + b1);
      *(_Float16*)(mb + (row << 8) + (((colg << 1)) ^ ((row & 7) << 4))) = (_Float16)v;
    }
  }
  __syncthreads();

  f32x16 acc2;
#pragma unroll
  for (int r = 0; r < 16; ++r) acc2[r] = 0.f;
#pragma unroll
  for (int t = 0; t < 8; ++t) {
    h8 a = *(const h8*)(mbc + (lrow << 8) + ((((t << 5) + (lhalf << 4))) ^ swz));
    h8 b = *(const h8*)&U2f[((((size_t)l * 4 + wave) * 8 + t) << 9) + (lane << 3)];
    acc2 = __builtin_amdgcn_mfma_f32_32x32x16_f16(a, b, acc2, 0, 0, 0);
  }
  {
    float b2 = ub2[l * Hc + colg];
#pragma unroll
    for (int r = 0; r < 16; ++r) {
      int row = (r & 3) + ((r >> 2) << 3) + (lhalf << 2);
      h[(size_t)(row0 + row) * Hc + colg] += acc2[r] + b2;   // rows exclusive, no atomics
    }
  }
}

// ---------------- readout ----------------

__global__ void readout_kernel(const float* __restrict__ h, const int* __restrict__ ent,
                               const float* __restrict__ oW1, const float* __restrict__ ob1,
                               const float* __restrict__ oW2, const float* __restrict__ ob2,
                               float* __restrict__ out) {
  __shared__ float tb[Bc][Hc];
  int tid = threadIdx.x;
  int b = tid >> 7, j = tid & 127;
  const float* e = &h[((size_t)(b * Nc + ent[b])) * Hc];
  float a = ob1[j];
#pragma unroll 4
  for (int i = 0; i < Hc; ++i) a = fmaf(e[i], oW1[i * Hc + j], a);
  tb[b][j] = silu_f(a);
  __syncthreads();
  if (tid < Bc) {
    float s = ob2[0];
    for (int i = 0; i < Hc; ++i) s = fmaf(tb[tid][i], oW2[i], s);
    out[tid] = s;
  }
}

// ---------------- host launcher ----------------

extern "C" void kernel_launch(void* const* d_in, const int* in_sizes, int n_in,
                              void* d_out, int out_size, void* d_ws, size_t ws_size,
                              hipStream_t stream) {
  const float* x    = (const float*)d_in[0];
  const float* bfe  = (const float*)d_in[1];
  const float* bp   = (const float*)d_in[2];
  const float* Win  = (const float*)d_in[3];
  const float* b_in = (const float*)d_in[4];
  const float* mW1  = (const float*)d_in[5];
  const float* mb1  = (const float*)d_in[6];
  const float* mW2  = (const float*)d_in[7];
  const float* mb2  = (const float*)d_in[8];
  const float* pW1  = (const float*)d_in[9];
  const float* pb1  = (const float*)d_in[10];
  const float* pW2  = (const float*)d_in[11];
  const float* pb2  = (const float*)d_in[12];
  const float* uW1  = (const float*)d_in[13];
  const float* ub1  = (const float*)d_in[14];
  const float* uW2  = (const float*)d_in[15];
  const float* ub2  = (const float*)d_in[16];
  const float* oW1  = (const float*)d_in[17];
  const float* ob1  = (const float*)d_in[18];
  const float* oW2  = (const float*)d_in[19];
  const float* ob2  = (const float*)d_in[20];
  const int* ent    = (const int*)d_in[21];
  const int* esrc   = (const int*)d_in[22];
  const int* edst   = (const int*)d_in[23];

  float* wsf = (float*)d_ws;
  float* h    = wsf;  wsf += (size_t)Bc * Nc * Hc;   // 2.56M
  float* msum = wsf;  wsf += (size_t)Bc * Nc * Hc;   // 2.56M
  float* pa   = wsf;  wsf += (size_t)Bc * Nc * 3;
  float* pb_  = wsf;  wsf += (size_t)Bc * Nc * 3;
  float* deg  = wsf;  wsf += (size_t)NBc * Nc;
  _Float16* W1f = (_Float16*)wsf;        // 196608 halfs (16B-aligned: prior floats sum to mult of 4)
  _Float16* W2f = W1f + 196608;
  _Float16* P1f = W2f + 98304;
  _Float16* U1f = P1f + 98304;
  _Float16* U2f = U1f + 65536;

  // weight fragment conversions (once per call; all blocks reuse from L2)
  conv_frag_kernel<<<dim3(768), dim3(256), 0, stream>>>(W1f, mW1, 16, 196608, 257L * 128);
  conv_frag_kernel<<<dim3(384), dim3(256), 0, stream>>>(W2f, mW2, 8, 98304, 128L * 128);
  conv_frag_kernel<<<dim3(384), dim3(256), 0, stream>>>(P1f, pW1, 8, 98304, 128L * 128);
  conv_frag_kernel<<<dim3(256), dim3(256), 0, stream>>>(U1f, uW1, 16, 65536, 256L * 128);
  conv_frag_kernel<<<dim3(128), dim3(256), 0, stream>>>(U2f, uW2, 8, 32768, 128L * 128);

  const int ndeg = NBc * Nc;
  zero4_kernel<<<dim3((ndeg / 4 + 255) / 256), dim3(256), 0, stream>>>(deg, ndeg / 4);
  count_deg_kernel<<<dim3((NBc * Ec + 255) / 256), dim3(256), 0, stream>>>(deg, edst);
  recip_deg_kernel<<<dim3((ndeg + 255) / 256), dim3(256), 0, stream>>>(deg);

  init_h_kernel<<<dim3((Bc * Nc * Hc + 255) / 256), dim3(256), 0, stream>>>(h, bfe, x, Win, b_in, ent);
  init_p_kernel<<<dim3((Bc * Nc * 3 + 255) / 256), dim3(256), 0, stream>>>(pa, bp);

  float* pcur = pa;
  float* pnew = pb_;
  const int nmh = Bc * Nc * Hc;
  for (int l = 0; l < Lc; ++l) {
    zero4_kernel<<<dim3((nmh / 4 + 255) / 256), dim3(256), 0, stream>>>(msum, nmh / 4);
    copy_kernel<<<dim3((Bc * Nc * 3 + 255) / 256), dim3(256), 0, stream>>>(pnew, pcur, Bc * Nc * 3);
    edge_mfma_kernel<<<dim3(Bc * Ec / 32, NBc), dim3(256), 0, stream>>>(
        h, pcur, msum, pnew, deg, esrc, edst,
        W1f, W2f, P1f, mW1, mb1, mb2, pb1, pW2, pb2, l);
    update_mfma_kernel<<<dim3(Bc * Nc / 32), dim3(256), 0, stream>>>(h, msum, U1f, U2f, ub1, ub2, l);
    float* t = pcur; pcur = pnew; pnew = t;
  }
  readout_kernel<<<dim3(1), dim3(256), 0, stream>>>(h, ent, oW1, ob1, oW2, ob2, (float*)d_out);
}

// Round 3
// 757.069 us; speedup vs baseline: 4.8800x; 1.1936x over previous
//
#include <hip/hip_runtime.h>
#include <hip/hip_bf16.h>
#include <math.h>

#define Bc   2
#define Nc   10000
#define Ec   100000
#define Hc   128
#define DINc 8
#define DBc  16
#define NBc  3
#define Lc   2
#define EB   3125   // Ec/32 blocks per batch element

typedef float v4 __attribute__((ext_vector_type(4)));
typedef float f32x16 __attribute__((ext_vector_type(16)));
typedef _Float16 h8 __attribute__((ext_vector_type(8)));
typedef _Float16 h4 __attribute__((ext_vector_type(4)));

__device__ __forceinline__ float silu_f(float x) { return x / (1.f + __expf(-x)); }

// ---------------- small utility kernels ----------------

__global__ void zero4_kernel(float* __restrict__ p, int n4) {
  int i = blockIdx.x * blockDim.x + threadIdx.x;
  if (i < n4) ((v4*)p)[i] = (v4)(0.f);
}

__global__ void copy_kernel(float* __restrict__ dst, const float* __restrict__ src, int n) {
  int i = blockIdx.x * blockDim.x + threadIdx.x;
  if (i < n) dst[i] = src[i];
}

// ---------------- sort-by-dst machinery (edge lists are constant inputs) ----------------

__global__ void hist_kernel(int* __restrict__ hist, const int* __restrict__ edst) {
  int i = blockIdx.x * blockDim.x + threadIdx.x;
  if (i < NBc * Ec) {
    int k = i / Ec;
    atomicAdd(&hist[k * Nc + edst[i]], 1);
  }
}

// one block per k: exclusive scan of hist -> offs; also deg_inv = 1/max(count,1)
__global__ void scan_kernel(const int* __restrict__ hist, int* __restrict__ offs,
                            float* __restrict__ deginv) {
  const int k = blockIdx.x, tid = threadIdx.x;
  const int NPT = 40;                      // 256*40 = 10240 >= Nc
  __shared__ int part[256];
  int local[NPT];
  int sum = 0;
  for (int j = 0; j < NPT; ++j) {
    int n = tid * NPT + j;
    if (n < Nc) { local[j] = sum; sum += hist[k * Nc + n]; }
  }
  part[tid] = sum;
  __syncthreads();
  for (int off = 1; off < 256; off <<= 1) {
    int v = (tid >= off) ? part[tid - off] : 0;
    __syncthreads();
    part[tid] += v;
    __syncthreads();
  }
  int excl = part[tid] - sum;
  for (int j = 0; j < NPT; ++j) {
    int n = tid * NPT + j;
    if (n < Nc) {
      offs[k * Nc + n] = excl + local[j];
      deginv[k * Nc + n] = 1.f / fmaxf((float)hist[k * Nc + n], 1.f);
    }
  }
}

__global__ void sort_scatter_kernel(int* __restrict__ sorted, int* __restrict__ cursor,
                                    const int* __restrict__ offs, const int* __restrict__ edst) {
  int i = blockIdx.x * blockDim.x + threadIdx.x;
  if (i < NBc * Ec) {
    int k = i / Ec, e = i - k * Ec;
    int d = edst[i];
    int pos = offs[k * Nc + d] + atomicAdd(&cursor[k * Nc + d], 1);
    sorted[k * Ec + pos] = e;
  }
}

// ---------------- init kernels ----------------

__global__ void init_h_kernel(_Float16* __restrict__ h16, const float* __restrict__ bfeat,
                              const float* __restrict__ x, const float* __restrict__ Win,
                              const float* __restrict__ b_in, const int* __restrict__ ent) {
  int g = blockIdx.x * blockDim.x + threadIdx.x;
  if (g >= Bc * Nc * Hc) return;
  int j = g & (Hc - 1);
  int bn = g >> 7;
  int n = bn % Nc;
  int b = bn / Nc;
  float acc = b_in[j];
#pragma unroll
  for (int i = 0; i < DBc; ++i) acc = fmaf(bfeat[n * DBc + i], Win[i * Hc + j], acc);
  if (n == ent[b]) {
#pragma unroll
    for (int i = 0; i < DINc; ++i) acc = fmaf(x[b * DINc + i], Win[(DBc + i) * Hc + j], acc);
  }
  h16[g] = (_Float16)acc;
}

__global__ void init_p_kernel(float* __restrict__ p, const float* __restrict__ bp) {
  int i = blockIdx.x * blockDim.x + threadIdx.x;
  if (i < Bc * Nc * 3) p[i] = bp[i % (Nc * 3)];
}

// ---------------- weight -> f16 MFMA-fragment-order conversion ----------------
__global__ void conv_frag_kernel(_Float16* __restrict__ dst, const float* __restrict__ src,
                                 int nchunk, int total, long srcStride) {
  int g = blockIdx.x * blockDim.x + threadIdx.x;
  if (g >= total) return;
  int j = g & 7;
  int lane = (g >> 3) & 63;
  int q = g >> 9;
  int t = q % nchunk;
  int q2 = q / nchunk;
  int wave = q2 & 3;
  int mat = q2 >> 2;
  int kk = t * 16 + (lane >> 5) * 8 + j;
  int col = wave * 32 + (lane & 31);
  dst[g] = (_Float16)src[(size_t)mat * srcStride + (size_t)kk * Hc + col];
}

// ---------------- fused edge MLP kernel (f16 MFMA, sorted edges, segmented scatter) ----------------
// grid (Bc*EB, NBc), 256 threads = 4 waves; 32 sorted edges/block.

__global__ __launch_bounds__(256, 4)
void edge_mfma_kernel(const _Float16* __restrict__ h16, const float* __restrict__ p,
                      float* __restrict__ m_sum, float* __restrict__ p_new,
                      const float* __restrict__ deginv,
                      const int* __restrict__ esrc, const int* __restrict__ edst,
                      const int* __restrict__ sorted,
                      const _Float16* __restrict__ W1f, const _Float16* __restrict__ W2f,
                      const _Float16* __restrict__ P1f,
                      const float* __restrict__ mW1, const float* __restrict__ mb1,
                      const float* __restrict__ mb2, const float* __restrict__ pb1,
                      const float* __restrict__ pW2, const float* __restrict__ pb2,
                      int l) {
  const int k = blockIdx.y, lk = l * NBc + k;
  const int b = (blockIdx.x >= EB) ? 1 : 0;
  const int pos0 = (blockIdx.x - b * EB) << 5;
  const int tid = threadIdx.x;
  const int wave = tid >> 6, lane = tid & 63;
  const int lrow = lane & 31, lhalf = lane >> 5;
  const int colg = (wave << 5) + lrow;

  __shared__ __align__(16) _Float16 Abuf[32 * 256];  // [h_dst|h_src], later m2 in first half
  __shared__ __align__(16) _Float16 Mbuf[32 * 128];  // m1
  __shared__ int shd[32], shs[32], sdi[32];
  __shared__ float sd2[32], sdinvs[32], srel[32][3], scoef[32];

  if (tid < 32) {
    int e = sorted[k * Ec + pos0 + tid];
    int si = esrc[k * Ec + e], di = edst[k * Ec + e];
    int nd = b * Nc + di, ns = b * Nc + si;
    const float* pd = &p[(size_t)nd * 3];
    const float* ps = &p[(size_t)ns * 3];
    float rx = pd[0] - ps[0], ry = pd[1] - ps[1], rz = pd[2] - ps[2];
    srel[tid][0] = rx; srel[tid][1] = ry; srel[tid][2] = rz;
    sd2[tid] = rx * rx + ry * ry + rz * rz;
    sdinvs[tid] = deginv[k * Nc + di];
    sdi[tid] = di;
    shd[tid] = nd * Hc; shs[tid] = ns * Hc;
    scoef[tid] = 0.f;
  }
  __syncthreads();

  // gather h16 rows -> Abuf (16B chunks, XOR swizzle byte^=(row&7)<<4)
  {
    const int i = tid >> 3, c = tid & 7;
    const int sw = (i & 7) << 4;
    char* ab = (char*)Abuf;
    h8 v0 = *(const h8*)&h16[shd[i] + c * 8];
    h8 v1 = *(const h8*)&h16[shd[i] + 64 + c * 8];
    h8 v2 = *(const h8*)&h16[shs[i] + c * 8];
    h8 v3 = *(const h8*)&h16[shs[i] + 64 + c * 8];
    *(h8*)(ab + (i << 9) + ((c * 16) ^ sw)) = v0;
    *(h8*)(ab + (i << 9) + ((128 + c * 16) ^ sw)) = v1;
    *(h8*)(ab + (i << 9) + ((256 + c * 16) ^ sw)) = v2;
    *(h8*)(ab + (i << 9) + ((384 + c * 16) ^ sw)) = v3;
  }
  __syncthreads();

  const int swz = (lrow & 7) << 4;
  const char* abc = (const char*)Abuf;
  const char* mbc = (const char*)Mbuf;

  // ---- GEMM1: [32,256]x[256,128] ----
  f32x16 acc;
#pragma unroll
  for (int r = 0; r < 16; ++r) acc[r] = 0.f;
#pragma unroll
  for (int t = 0; t < 16; ++t) {
    h8 a = *(const h8*)(abc + (lrow << 9) + ((((t << 5) + (lhalf << 4))) ^ swz));
    h8 bf = *(const h8*)&W1f[((((size_t)lk * 4 + wave) * 16 + t) << 9) + (lane << 3)];
    acc = __builtin_amdgcn_mfma_f32_32x32x16_f16(a, bf, acc, 0, 0, 0);
  }
  {
    float wl = mW1[((size_t)lk * 257 + 256) * Hc + colg];
    float b1 = mb1[lk * Hc + colg];
    char* mb = (char*)Mbuf;
#pragma unroll
    for (int r = 0; r < 16; ++r) {
      int row = (r & 3) + ((r >> 2) << 3) + (lhalf << 2);
      float v = silu_f(acc[r] + sd2[row] * wl + b1);
      *(_Float16*)(mb + (row << 8) + (((colg << 1)) ^ ((row & 7) << 4))) = (_Float16)v;
    }
  }
  __syncthreads();

  // ---- GEMM2: m2 = silu(m1 @ W2 + b2) ----
  f32x16 acc2;
#pragma unroll
  for (int r = 0; r < 16; ++r) acc2[r] = 0.f;
#pragma unroll
  for (int t = 0; t < 8; ++t) {
    h8 a = *(const h8*)(mbc + (lrow << 8) + ((((t << 5) + (lhalf << 4))) ^ swz));
    h8 bf = *(const h8*)&W2f[((((size_t)lk * 4 + wave) * 8 + t) << 9) + (lane << 3)];
    acc2 = __builtin_amdgcn_mfma_f32_32x32x16_f16(a, bf, acc2, 0, 0, 0);
  }
  {
    float b2 = mb2[lk * Hc + colg];
    char* ab = (char*)Abuf;
#pragma unroll
    for (int r = 0; r < 16; ++r) {
      int row = (r & 3) + ((r >> 2) << 3) + (lhalf << 2);
      float v = silu_f(acc2[r] + b2);
      *(_Float16*)(ab + (row << 9) + (((colg << 1)) ^ ((row & 7) << 4))) = (_Float16)v;  // m2
    }
  }
  __syncthreads();

  // ---- GEMM3: coef = (silu(m2 @ posW1 + posb1) . posW2) + posb2 ----
  f32x16 acc3;
#pragma unroll
  for (int r = 0; r < 16; ++r) acc3[r] = 0.f;
#pragma unroll
  for (int t = 0; t < 8; ++t) {
    h8 a = *(const h8*)(abc + (lrow << 9) + ((((t << 5) + (lhalf << 4))) ^ swz));
    h8 bf = *(const h8*)&P1f[((((size_t)lk * 4 + wave) * 8 + t) << 9) + (lane << 3)];
    acc3 = __builtin_amdgcn_mfma_f32_32x32x16_f16(a, bf, acc3, 0, 0, 0);
  }
  {
    float pb1v = pb1[lk * Hc + colg];
    float pw2v = pW2[lk * Hc + colg];
#pragma unroll
    for (int r = 0; r < 16; ++r) {
      float q = silu_f(acc3[r] + pb1v) * pw2v;
#pragma unroll
      for (int off = 16; off >= 1; off >>= 1) q += __shfl_xor(q, off);
      if (lrow == 0) {
        int row = (r & 3) + ((r >> 2) << 3) + (lhalf << 2);
        atomicAdd(&scoef[row], q);
      }
    }
  }
  __syncthreads();

  // ---- segmented m_sum scatter: rows are sorted by dst within the block ----
  {
    const int col = tid & 127;
    const int r0 = (tid >> 7) << 4;     // 0 or 16
    const size_t bbase = (size_t)b * Nc * Hc;
    float accv = 0.f, cinv = 0.f;
    int cur = -1;
    for (int r = r0; r < r0 + 16; ++r) {   // dst uniform across lanes -> no divergence
      float v = (float)*(const _Float16*)(abc + (r << 9) + (((col << 1)) ^ ((r & 7) << 4)));
      int d = sdi[r];
      if (d != cur) {
        if (cur >= 0) atomicAdd(&m_sum[bbase + (size_t)cur * Hc + col], accv * cinv);
        cur = d; cinv = sdinvs[r]; accv = v;
      } else accv += v;
    }
    atomicAdd(&m_sum[bbase + (size_t)cur * Hc + col], accv * cinv);
  }
  // ---- p_new scatter ----
  if (tid < 32) {
    float cf = (scoef[tid] + pb2[lk]) * sdinvs[tid];
    float* pp = &p_new[((size_t)(b * Nc + sdi[tid])) * 3];
    atomicAdd(&pp[0], srel[tid][0] * cf);
    atomicAdd(&pp[1], srel[tid][1] * cf);
    atomicAdd(&pp[2], srel[tid][2] * cf);
  }
}

// ---------------- node update kernel (f16 MFMA, h16 in/out) ----------------

__global__ __launch_bounds__(256, 4)
void update_mfma_kernel(_Float16* __restrict__ h16, const float* __restrict__ m_sum,
                        const _Float16* __restrict__ U1f, const _Float16* __restrict__ U2f,
                        const float* __restrict__ ub1, const float* __restrict__ ub2, int l) {
  const int tid = threadIdx.x;
  const int wave = tid >> 6, lane = tid & 63;
  const int lrow = lane & 31, lhalf = lane >> 5;
  const int colg = (wave << 5) + lrow;
  const int row0 = blockIdx.x << 5;

  __shared__ __align__(16) _Float16 Abuf[32 * 256];
  __shared__ __align__(16) _Float16 Mbuf[32 * 128];

  {
    const int i = tid >> 3, c = tid & 7;
    const int sw = (i & 7) << 4;
    char* ab = (char*)Abuf;
    size_t hb = (size_t)(row0 + i) * Hc;
    h8 v0 = *(const h8*)&h16[hb + c * 8];
    h8 v1 = *(const h8*)&h16[hb + 64 + c * 8];
    *(h8*)(ab + (i << 9) + ((c * 16) ^ sw)) = v0;
    *(h8*)(ab + (i << 9) + ((128 + c * 16) ^ sw)) = v1;
#pragma unroll
    for (int q = 0; q < 4; ++q) {
      v4 mv = *(const v4*)&m_sum[hb + c * 4 + q * 32];
      h4 mh;
#pragma unroll
      for (int z = 0; z < 4; ++z) mh[z] = (_Float16)mv[z];
      *(h4*)(ab + (i << 9) + ((256 + q * 64 + c * 8) ^ sw)) = mh;
    }
  }
  __syncthreads();

  const int swz = (lrow & 7) << 4;
  const char* abc = (const char*)Abuf;
  const char* mbc = (const char*)Mbuf;

  f32x16 acc;
#pragma unroll
  for (int r = 0; r < 16; ++r) acc[r] = 0.f;
#pragma unroll
  for (int t = 0; t < 16; ++t) {
    h8 a = *(const h8*)(abc + (lrow << 9) + ((((t << 5) + (lhalf << 4))) ^ swz));
    h8 bf = *(const h8*)&U1f[((((size_t)l * 4 + wave) * 16 + t) << 9) + (lane << 3)];
    acc = __builtin_amdgcn_mfma_f32_32x32x16_f16(a, bf, acc, 0, 0, 0);
  }
  {
    float b1 = ub1[l * Hc + colg];
    char* mb = (char*)Mbuf;
#pragma unroll
    for (int r = 0; r < 16; ++r) {
      int row = (r & 3) + ((r >> 2) << 3) + (lhalf << 2);
      float v = silu_f(acc[r] + b1);
      *(_Float16*)(mb + (row << 8) + (((colg << 1)) ^ ((row & 7) << 4))) = (_Float16)v;
    }
  }
  __syncthreads();

  f32x16 acc2;
#pragma unroll
  for (int r = 0; r < 16; ++r) acc2[r] = 0.f;
#pragma unroll
  for (int t = 0; t < 8; ++t) {
    h8 a = *(const h8*)(mbc + (lrow << 8) + ((((t << 5) + (lhalf << 4))) ^ swz));
    h8 bf = *(const h8*)&U2f[((((size_t)l * 4 + wave) * 8 + t) << 9) + (lane << 3)];
    acc2 = __builtin_amdgcn_mfma_f32_32x32x16_f16(a, bf, acc2, 0, 0, 0);
  }
  {
    float b2 = ub2[l * Hc + colg];
#pragma unroll
    for (int r = 0; r < 16; ++r) {
      int row = (r & 3) + ((r >> 2) << 3) + (lhalf << 2);
      size_t idx = (size_t)(row0 + row) * Hc + colg;
      h16[idx] = (_Float16)((float)h16[idx] + acc2[r] + b2);
    }
  }
}

// ---------------- readout ----------------

__global__ void readout_kernel(const _Float16* __restrict__ h16, const int* __restrict__ ent,
                               const float* __restrict__ oW1, const float* __restrict__ ob1,
                               const float* __restrict__ oW2, const float* __restrict__ ob2,
                               float* __restrict__ out) {
  __shared__ float tb[Bc][Hc];
  int tid = threadIdx.x;
  int b = tid >> 7, j = tid & 127;
  const _Float16* e = &h16[((size_t)(b * Nc + ent[b])) * Hc];
  float a = ob1[j];
#pragma unroll 4
  for (int i = 0; i < Hc; ++i) a = fmaf((float)e[i], oW1[i * Hc + j], a);
  tb[b][j] = silu_f(a);
  __syncthreads();
  if (tid < Bc) {
    float s = ob2[0];
    for (int i = 0; i < Hc; ++i) s = fmaf(tb[tid][i], oW2[i], s);
    out[tid] = s;
  }
}

// ---------------- host launcher ----------------

extern "C" void kernel_launch(void* const* d_in, const int* in_sizes, int n_in,
                              void* d_out, int out_size, void* d_ws, size_t ws_size,
                              hipStream_t stream) {
  const float* x    = (const float*)d_in[0];
  const float* bfe  = (const float*)d_in[1];
  const float* bp   = (const float*)d_in[2];
  const float* Win  = (const float*)d_in[3];
  const float* b_in = (const float*)d_in[4];
  const float* mW1  = (const float*)d_in[5];
  const float* mb1  = (const float*)d_in[6];
  const float* mW2  = (const float*)d_in[7];
  const float* mb2  = (const float*)d_in[8];
  const float* pW1  = (const float*)d_in[9];
  const float* pb1  = (const float*)d_in[10];
  const float* pW2  = (const float*)d_in[11];
  const float* pb2  = (const float*)d_in[12];
  const float* uW1  = (const float*)d_in[13];
  const float* ub1  = (const float*)d_in[14];
  const float* uW2  = (const float*)d_in[15];
  const float* ub2  = (const float*)d_in[16];
  const float* oW1  = (const float*)d_in[17];
  const float* ob1  = (const float*)d_in[18];
  const float* oW2  = (const float*)d_in[19];
  const float* ob2  = (const float*)d_in[20];
  const int* ent    = (const int*)d_in[21];
  const int* esrc   = (const int*)d_in[22];
  const int* edst   = (const int*)d_in[23];

  float* wsf = (float*)d_ws;
  float* msum   = wsf;  wsf += (size_t)Bc * Nc * Hc;   // 2,560,000
  float* pa     = wsf;  wsf += (size_t)Bc * Nc * 3;
  float* pb_    = wsf;  wsf += (size_t)Bc * Nc * 3;
  float* deginv = wsf;  wsf += (size_t)NBc * Nc;
  _Float16* h16 = (_Float16*)wsf;
  _Float16* W1f = h16 + (size_t)Bc * Nc * Hc;
  _Float16* W2f = W1f + 196608;
  _Float16* P1f = W2f + 98304;
  _Float16* U1f = P1f + 98304;
  _Float16* U2f = U1f + 65536;
  int* hist   = (int*)(U2f + 32768);
  int* cursor = hist + NBc * Nc;
  int* offs   = cursor + NBc * Nc;
  int* sorted = offs + NBc * Nc;

  // --- sort edges by dst (once per call; hist doubles as degree) ---
  zero4_kernel<<<dim3((2 * NBc * Nc / 4 + 255) / 256), dim3(256), 0, stream>>>((float*)hist, 2 * NBc * Nc / 4);
  hist_kernel<<<dim3((NBc * Ec + 255) / 256), dim3(256), 0, stream>>>(hist, edst);
  scan_kernel<<<dim3(NBc), dim3(256), 0, stream>>>(hist, offs, deginv);
  sort_scatter_kernel<<<dim3((NBc * Ec + 255) / 256), dim3(256), 0, stream>>>(sorted, cursor, offs, edst);

  // --- weight fragment conversions ---
  conv_frag_kernel<<<dim3(768), dim3(256), 0, stream>>>(W1f, mW1, 16, 196608, 257L * 128);
  conv_frag_kernel<<<dim3(384), dim3(256), 0, stream>>>(W2f, mW2, 8, 98304, 128L * 128);
  conv_frag_kernel<<<dim3(384), dim3(256), 0, stream>>>(P1f, pW1, 8, 98304, 128L * 128);
  conv_frag_kernel<<<dim3(256), dim3(256), 0, stream>>>(U1f, uW1, 16, 65536, 256L * 128);
  conv_frag_kernel<<<dim3(128), dim3(256), 0, stream>>>(U2f, uW2, 8, 32768, 128L * 128);

  init_h_kernel<<<dim3((Bc * Nc * Hc + 255) / 256), dim3(256), 0, stream>>>(h16, bfe, x, Win, b_in, ent);
  init_p_kernel<<<dim3((Bc * Nc * 3 + 255) / 256), dim3(256), 0, stream>>>(pa, bp);

  float* pcur = pa;
  float* pnew = pb_;
  const int nmh = Bc * Nc * Hc;
  for (int l = 0; l < Lc; ++l) {
    zero4_kernel<<<dim3((nmh / 4 + 255) / 256), dim3(256), 0, stream>>>(msum, nmh / 4);
    copy_kernel<<<dim3((Bc * Nc * 3 + 255) / 256), dim3(256), 0, stream>>>(pnew, pcur, Bc * Nc * 3);
    edge_mfma_kernel<<<dim3(Bc * EB, NBc), dim3(256), 0, stream>>>(
        h16, pcur, msum, pnew, deginv, esrc, edst, sorted,
        W1f, W2f, P1f, mW1, mb1, mb2, pb1, pW2, pb2, l);
    update_mfma_kernel<<<dim3(Bc * Nc / 32), dim3(256), 0, stream>>>(h16, msum, U1f, U2f, ub1, ub2, l);
    float* t = pcur; pcur = pnew; pnew = t;
  }
  readout_kernel<<<dim3(1), dim3(256), 0, stream>>>(h16, ent, oW1, ob1, oW2, ob2, (float*)d_out);
}

// Round 4
// 721.973 us; speedup vs baseline: 5.1172x; 1.0486x over previous
//
#include <hip/hip_runtime.h>
#include <hip/hip_bf16.h>
#include <math.h>

#define Bc   2
#define Nc   10000
#define Ec   100000
#define Hc   128
#define DINc 8
#define DBc  16
#define NBc  3
#define Lc   2
#define EB   3125   // Ec/32 blocks per batch element

typedef float v4 __attribute__((ext_vector_type(4)));
typedef float f32x16 __attribute__((ext_vector_type(16)));
typedef _Float16 h8 __attribute__((ext_vector_type(8)));
typedef _Float16 h4 __attribute__((ext_vector_type(4)));

__device__ __forceinline__ float silu_f(float x) { return x / (1.f + __expf(-x)); }

// ---------------- small utility kernels ----------------

__global__ void zero4_kernel(float* __restrict__ p, int n4) {
  int i = blockIdx.x * blockDim.x + threadIdx.x;
  if (i < n4) ((v4*)p)[i] = (v4)(0.f);
}

__global__ void copy_kernel(float* __restrict__ dst, const float* __restrict__ src, int n) {
  int i = blockIdx.x * blockDim.x + threadIdx.x;
  if (i < n) dst[i] = src[i];
}

// ---------------- sort-by-dst machinery (edge lists are constant inputs) ----------------

__global__ void hist_kernel(int* __restrict__ hist, const int* __restrict__ edst) {
  int i = blockIdx.x * blockDim.x + threadIdx.x;
  if (i < NBc * Ec) {
    int k = i / Ec;
    atomicAdd(&hist[k * Nc + edst[i]], 1);
  }
}

__global__ void scan_kernel(const int* __restrict__ hist, int* __restrict__ offs,
                            float* __restrict__ deginv) {
  const int k = blockIdx.x, tid = threadIdx.x;
  const int NPT = 40;
  __shared__ int part[256];
  int local[NPT];
  int sum = 0;
  for (int j = 0; j < NPT; ++j) {
    int n = tid * NPT + j;
    if (n < Nc) { local[j] = sum; sum += hist[k * Nc + n]; }
  }
  part[tid] = sum;
  __syncthreads();
  for (int off = 1; off < 256; off <<= 1) {
    int v = (tid >= off) ? part[tid - off] : 0;
    __syncthreads();
    part[tid] += v;
    __syncthreads();
  }
  int excl = part[tid] - sum;
  for (int j = 0; j < NPT; ++j) {
    int n = tid * NPT + j;
    if (n < Nc) {
      offs[k * Nc + n] = excl + local[j];
      deginv[k * Nc + n] = 1.f / fmaxf((float)hist[k * Nc + n], 1.f);
    }
  }
}

__global__ void sort_scatter_kernel(int* __restrict__ sorted, int* __restrict__ cursor,
                                    const int* __restrict__ offs, const int* __restrict__ edst) {
  int i = blockIdx.x * blockDim.x + threadIdx.x;
  if (i < NBc * Ec) {
    int k = i / Ec, e = i - k * Ec;
    int d = edst[i];
    int pos = offs[k * Nc + d] + atomicAdd(&cursor[k * Nc + d], 1);
    sorted[k * Ec + pos] = e;
  }
}

// ---------------- init kernels ----------------

__global__ void init_h_kernel(_Float16* __restrict__ h16, const float* __restrict__ bfeat,
                              const float* __restrict__ x, const float* __restrict__ Win,
                              const float* __restrict__ b_in, const int* __restrict__ ent) {
  int g = blockIdx.x * blockDim.x + threadIdx.x;
  if (g >= Bc * Nc * Hc) return;
  int j = g & (Hc - 1);
  int bn = g >> 7;
  int n = bn % Nc;
  int b = bn / Nc;
  float acc = b_in[j];
#pragma unroll
  for (int i = 0; i < DBc; ++i) acc = fmaf(bfeat[n * DBc + i], Win[i * Hc + j], acc);
  if (n == ent[b]) {
#pragma unroll
    for (int i = 0; i < DINc; ++i) acc = fmaf(x[b * DINc + i], Win[(DBc + i) * Hc + j], acc);
  }
  h16[g] = (_Float16)acc;
}

__global__ void init_p_kernel(float* __restrict__ p, const float* __restrict__ bp) {
  int i = blockIdx.x * blockDim.x + threadIdx.x;
  if (i < Bc * Nc * 3) p[i] = bp[i % (Nc * 3)];
}

// ---------------- weight -> f16 MFMA-fragment-order conversion ----------------
// frag[lane, t, j] = src[kk = t*16 + (lane>>5)*8 + j][col = wave*32 + (lane&31)]
// (same layout serves as B-operand (act@W) or A-operand (W^T @ act^T) by symmetry)
__global__ void conv_frag_kernel(_Float16* __restrict__ dst, const float* __restrict__ src,
                                 int nchunk, int total, long srcStride) {
  int g = blockIdx.x * blockDim.x + threadIdx.x;
  if (g >= total) return;
  int j = g & 7;
  int lane = (g >> 3) & 63;
  int q = g >> 9;
  int t = q % nchunk;
  int q2 = q / nchunk;
  int wave = q2 & 3;
  int mat = q2 >> 2;
  int kk = t * 16 + (lane >> 5) * 8 + j;
  int col = wave * 32 + (lane & 31);
  dst[g] = (_Float16)src[(size_t)mat * srcStride + (size_t)kk * Hc + col];
}

// ---------------- fused edge MLP kernel (swapped-operand f16 MFMA) ----------------
// grid (Bc*EB, NBc), 256 threads = 4 waves; 32 sorted edges/block.
// All GEMMs compute C^T = W^T @ act^T via mfma(W_frag, act_frag): each lane owns
// a fixed edge-row (lane&31) and 16 h-cols in 4 runs of 4 -> vector b64 epilogue
// writes, lane-local pos-MLP reduction.

__global__ __launch_bounds__(256, 4)
void edge_mfma_kernel(const _Float16* __restrict__ h16, const float* __restrict__ p,
                      float* __restrict__ m_sum, float* __restrict__ p_new,
                      const float* __restrict__ deginv,
                      const int* __restrict__ esrc, const int* __restrict__ edst,
                      const int* __restrict__ sorted,
                      const _Float16* __restrict__ W1f, const _Float16* __restrict__ W2f,
                      const _Float16* __restrict__ P1f,
                      const float* __restrict__ mW1, const float* __restrict__ mb1,
                      const float* __restrict__ mb2, const float* __restrict__ pb1,
                      const float* __restrict__ pW2, const float* __restrict__ pb2,
                      int l) {
  const int k = blockIdx.y, lk = l * NBc + k;
  const int b = (blockIdx.x >= EB) ? 1 : 0;
  const int pos0 = (blockIdx.x - b * EB) << 5;
  const int tid = threadIdx.x;
  const int wave = tid >> 6, lane = tid & 63;
  const int lrow = lane & 31, lhalf = lane >> 5;

  __shared__ __align__(16) _Float16 Abuf[32 * 256];  // [h_dst|h_src] per edge row; later m2 in bytes 0..255
  __shared__ __align__(16) _Float16 Mbuf[32 * 128];  // m1
  __shared__ int shd[32], shs[32], sdi[32];
  __shared__ float sd2[32], sdinvs[32], srel[32][3], scoef[32];
  __shared__ float cw1[Hc], cb1[Hc], cb2[Hc], cpb1[Hc], cpw2[Hc];  // epilogue constants

  if (tid < Hc) {
    cw1[tid]  = mW1[((size_t)lk * 257 + 256) * Hc + tid];  // d2 row of W1
    cb1[tid]  = mb1[lk * Hc + tid];
    cb2[tid]  = mb2[lk * Hc + tid];
    cpb1[tid] = pb1[lk * Hc + tid];
    cpw2[tid] = pW2[lk * Hc + tid];
  }
  if (tid < 32) {
    int e = sorted[k * Ec + pos0 + tid];
    int si = esrc[k * Ec + e], di = edst[k * Ec + e];
    int nd = b * Nc + di, ns = b * Nc + si;
    const float* pd = &p[(size_t)nd * 3];
    const float* ps = &p[(size_t)ns * 3];
    float rx = pd[0] - ps[0], ry = pd[1] - ps[1], rz = pd[2] - ps[2];
    srel[tid][0] = rx; srel[tid][1] = ry; srel[tid][2] = rz;
    sd2[tid] = rx * rx + ry * ry + rz * rz;
    sdinvs[tid] = deginv[k * Nc + di];
    sdi[tid] = di;
    shd[tid] = nd * Hc; shs[tid] = ns * Hc;
    scoef[tid] = 0.f;
  }
  __syncthreads();

  // gather h16 rows -> Abuf (16B chunks, XOR swizzle byte^=(row&7)<<4)
  {
    const int i = tid >> 3, c = tid & 7;
    const int sw = (i & 7) << 4;
    char* ab = (char*)Abuf;
    h8 v0 = *(const h8*)&h16[shd[i] + c * 8];
    h8 v1 = *(const h8*)&h16[shd[i] + 64 + c * 8];
    h8 v2 = *(const h8*)&h16[shs[i] + c * 8];
    h8 v3 = *(const h8*)&h16[shs[i] + 64 + c * 8];
    *(h8*)(ab + (i << 9) + ((c * 16) ^ sw)) = v0;
    *(h8*)(ab + (i << 9) + ((128 + c * 16) ^ sw)) = v1;
    *(h8*)(ab + (i << 9) + ((256 + c * 16) ^ sw)) = v2;
    *(h8*)(ab + (i << 9) + ((384 + c * 16) ^ sw)) = v3;
  }
  __syncthreads();

  const int swz = (lrow & 7) << 4;
  const char* abc = (const char*)Abuf;
  const char* mbc = (const char*)Mbuf;

  // ---- GEMM1^T: m1^T = W1^T @ [hd|hs]^T ----
  f32x16 acc;
#pragma unroll
  for (int r = 0; r < 16; ++r) acc[r] = 0.f;
#pragma unroll
  for (int t = 0; t < 16; ++t) {
    h8 bact = *(const h8*)(abc + (lrow << 9) + ((((t << 5) + (lhalf << 4))) ^ swz));
    h8 aw = *(const h8*)&W1f[((((size_t)lk * 4 + wave) * 16 + t) << 9) + (lane << 3)];
    acc = __builtin_amdgcn_mfma_f32_32x32x16_f16(aw, bact, acc, 0, 0, 0);
  }
  {
    float d2e = sd2[lrow];
    char* mb = (char*)Mbuf;
#pragma unroll
    for (int c = 0; c < 4; ++c) {
      int hb = (wave << 5) + (c << 3) + (lhalf << 2);   // 4 consecutive h at hb..hb+3
      h4 pk;
#pragma unroll
      for (int z = 0; z < 4; ++z)
        pk[z] = (_Float16)silu_f(acc[c * 4 + z] + d2e * cw1[hb + z] + cb1[hb + z]);
      *(h4*)(mb + (lrow << 8) + (((hb << 1)) ^ swz)) = pk;
    }
  }
  __syncthreads();

  // ---- GEMM2^T: m2^T = W2^T @ m1^T ----
  f32x16 acc2;
#pragma unroll
  for (int r = 0; r < 16; ++r) acc2[r] = 0.f;
#pragma unroll
  for (int t = 0; t < 8; ++t) {
    h8 bact = *(const h8*)(mbc + (lrow << 8) + ((((t << 5) + (lhalf << 4))) ^ swz));
    h8 aw = *(const h8*)&W2f[((((size_t)lk * 4 + wave) * 8 + t) << 9) + (lane << 3)];
    acc2 = __builtin_amdgcn_mfma_f32_32x32x16_f16(aw, bact, acc2, 0, 0, 0);
  }
  {
    char* ab = (char*)Abuf;
#pragma unroll
    for (int c = 0; c < 4; ++c) {
      int hb = (wave << 5) + (c << 3) + (lhalf << 2);
      h4 pk;
#pragma unroll
      for (int z = 0; z < 4; ++z)
        pk[z] = (_Float16)silu_f(acc2[c * 4 + z] + cb2[hb + z]);
      *(h4*)(ab + (lrow << 9) + (((hb << 1)) ^ swz)) = pk;                 // m2
    }
  }
  __syncthreads();

  // ---- GEMM3^T: q^T = P1^T @ m2^T; coef = sum_h silu(q)*pW2 (lane-local) ----
  f32x16 acc3;
#pragma unroll
  for (int r = 0; r < 16; ++r) acc3[r] = 0.f;
#pragma unroll
  for (int t = 0; t < 8; ++t) {
    h8 bact = *(const h8*)(abc + (lrow << 9) + ((((t << 5) + (lhalf << 4))) ^ swz));
    h8 aw = *(const h8*)&P1f[((((size_t)lk * 4 + wave) * 8 + t) << 9) + (lane << 3)];
    acc3 = __builtin_amdgcn_mfma_f32_32x32x16_f16(aw, bact, acc3, 0, 0, 0);
  }
  {
    float csum = 0.f;
#pragma unroll
    for (int r = 0; r < 16; ++r) {
      int hg = (wave << 5) + (r & 3) + (((r >> 2)) << 3) + (lhalf << 2);
      csum += silu_f(acc3[r] + cpb1[hg]) * cpw2[hg];
    }
    csum += __shfl_down(csum, 32);
    if (lane < 32) atomicAdd(&scoef[lrow], csum);
  }
  __syncthreads();

  // ---- segmented m_sum scatter: rows sorted by dst within the block ----
  {
    const int col = tid & 127;
    const int r0 = (tid >> 7) << 4;     // 0 or 16
    const size_t bbase = (size_t)b * Nc * Hc;
    float accv = 0.f, cinv = 0.f;
    int cur = -1;
    for (int r = r0; r < r0 + 16; ++r) {   // dst uniform across lanes -> no divergence
      float v = (float)*(const _Float16*)(abc + (r << 9) + (((col << 1)) ^ ((r & 7) << 4)));
      int d = sdi[r];
      if (d != cur) {
        if (cur >= 0) atomicAdd(&m_sum[bbase + (size_t)cur * Hc + col], accv * cinv);
        cur = d; cinv = sdinvs[r]; accv = v;
      } else accv += v;
    }
    atomicAdd(&m_sum[bbase + (size_t)cur * Hc + col], accv * cinv);
  }
  // ---- p_new scatter ----
  if (tid < 32) {
    float cf = (scoef[tid] + pb2[lk]) * sdinvs[tid];
    float* pp = &p_new[((size_t)(b * Nc + sdi[tid])) * 3];
    atomicAdd(&pp[0], srel[tid][0] * cf);
    atomicAdd(&pp[1], srel[tid][1] * cf);
    atomicAdd(&pp[2], srel[tid][2] * cf);
  }
}

// ---------------- node update kernel (swapped-operand f16 MFMA) ----------------

__global__ __launch_bounds__(256, 4)
void update_mfma_kernel(_Float16* __restrict__ h16, const float* __restrict__ m_sum,
                        const _Float16* __restrict__ U1f, const _Float16* __restrict__ U2f,
                        const float* __restrict__ ub1, const float* __restrict__ ub2, int l) {
  const int tid = threadIdx.x;
  const int wave = tid >> 6, lane = tid & 63;
  const int lrow = lane & 31, lhalf = lane >> 5;
  const int row0 = blockIdx.x << 5;

  __shared__ __align__(16) _Float16 Abuf[32 * 256];
  __shared__ __align__(16) _Float16 Mbuf[32 * 128];
  __shared__ float cu1[Hc], cu2[Hc];

  if (tid < Hc) { cu1[tid] = ub1[l * Hc + tid]; cu2[tid] = ub2[l * Hc + tid]; }

  {
    const int i = tid >> 3, c = tid & 7;
    const int sw = (i & 7) << 4;
    char* ab = (char*)Abuf;
    size_t hb = (size_t)(row0 + i) * Hc;
    h8 v0 = *(const h8*)&h16[hb + c * 8];
    h8 v1 = *(const h8*)&h16[hb + 64 + c * 8];
    *(h8*)(ab + (i << 9) + ((c * 16) ^ sw)) = v0;
    *(h8*)(ab + (i << 9) + ((128 + c * 16) ^ sw)) = v1;
#pragma unroll
    for (int q = 0; q < 4; ++q) {
      v4 mv = *(const v4*)&m_sum[hb + c * 4 + q * 32];
      h4 mh;
#pragma unroll
      for (int z = 0; z < 4; ++z) mh[z] = (_Float16)mv[z];
      *(h4*)(ab + (i << 9) + ((256 + q * 64 + c * 8) ^ sw)) = mh;
    }
  }
  __syncthreads();

  const int swz = (lrow & 7) << 4;
  const char* abc = (const char*)Abuf;
  const char* mbc = (const char*)Mbuf;

  f32x16 acc;
#pragma unroll
  for (int r = 0; r < 16; ++r) acc[r] = 0.f;
#pragma unroll
  for (int t = 0; t < 16; ++t) {
    h8 bact = *(const h8*)(abc + (lrow << 9) + ((((t << 5) + (lhalf << 4))) ^ swz));
    h8 aw = *(const h8*)&U1f[((((size_t)l * 4 + wave) * 16 + t) << 9) + (lane << 3)];
    acc = __builtin_amdgcn_mfma_f32_32x32x16_f16(aw, bact, acc, 0, 0, 0);
  }
  {
    char* mb = (char*)Mbuf;
#pragma unroll
    for (int c = 0; c < 4; ++c) {
      int hb = (wave << 5) + (c << 3) + (lhalf << 2);
      h4 pk;
#pragma unroll
      for (int z = 0; z < 4; ++z)
        pk[z] = (_Float16)silu_f(acc[c * 4 + z] + cu1[hb + z]);
      *(h4*)(mb + (lrow << 8) + (((hb << 1)) ^ swz)) = pk;
    }
  }
  __syncthreads();

  f32x16 acc2;
#pragma unroll
  for (int r = 0; r < 16; ++r) acc2[r] = 0.f;
#pragma unroll
  for (int t = 0; t < 8; ++t) {
    h8 bact = *(const h8*)(mbc + (lrow << 8) + ((((t << 5) + (lhalf << 4))) ^ swz));
    h8 aw = *(const h8*)&U2f[((((size_t)l * 4 + wave) * 8 + t) << 9) + (lane << 3)];
    acc2 = __builtin_amdgcn_mfma_f32_32x32x16_f16(aw, bact, acc2, 0, 0, 0);
  }
  {
    _Float16* hp = &h16[(size_t)(row0 + lrow) * Hc];
#pragma unroll
    for (int c = 0; c < 4; ++c) {
      int hb = (wave << 5) + (c << 3) + (lhalf << 2);
      h4 old = *(const h4*)&hp[hb];
      h4 nv;
#pragma unroll
      for (int z = 0; z < 4; ++z)
        nv[z] = (_Float16)((float)old[z] + acc2[c * 4 + z] + cu2[hb + z]);
      *(h4*)&hp[hb] = nv;            // rows exclusive to block, chunks disjoint
    }
  }
}

// ---------------- readout ----------------

__global__ void readout_kernel(const _Float16* __restrict__ h16, const int* __restrict__ ent,
                               const float* __restrict__ oW1, const float* __restrict__ ob1,
                               const float* __restrict__ oW2, const float* __restrict__ ob2,
                               float* __restrict__ out) {
  __shared__ float tb[Bc][Hc];
  int tid = threadIdx.x;
  int b = tid >> 7, j = tid & 127;
  const _Float16* e = &h16[((size_t)(b * Nc + ent[b])) * Hc];
  float a = ob1[j];
#pragma unroll 4
  for (int i = 0; i < Hc; ++i) a = fmaf((float)e[i], oW1[i * Hc + j], a);
  tb[b][j] = silu_f(a);
  __syncthreads();
  if (tid < Bc) {
    float s = ob2[0];
    for (int i = 0; i < Hc; ++i) s = fmaf(tb[tid][i], oW2[i], s);
    out[tid] = s;
  }
}

// ---------------- host launcher ----------------

extern "C" void kernel_launch(void* const* d_in, const int* in_sizes, int n_in,
                              void* d_out, int out_size, void* d_ws, size_t ws_size,
                              hipStream_t stream) {
  const float* x    = (const float*)d_in[0];
  const float* bfe  = (const float*)d_in[1];
  const float* bp   = (const float*)d_in[2];
  const float* Win  = (const float*)d_in[3];
  const float* b_in = (const float*)d_in[4];
  const float* mW1  = (const float*)d_in[5];
  const float* mb1  = (const float*)d_in[6];
  const float* mW2  = (const float*)d_in[7];
  const float* mb2  = (const float*)d_in[8];
  const float* pW1  = (const float*)d_in[9];
  const float* pb1  = (const float*)d_in[10];
  const float* pW2  = (const float*)d_in[11];
  const float* pb2  = (const float*)d_in[12];
  const float* uW1  = (const float*)d_in[13];
  const float* ub1  = (const float*)d_in[14];
  const float* uW2  = (const float*)d_in[15];
  const float* ub2  = (const float*)d_in[16];
  const float* oW1  = (const float*)d_in[17];
  const float* ob1  = (const float*)d_in[18];
  const float* oW2  = (const float*)d_in[19];
  const float* ob2  = (const float*)d_in[20];
  const int* ent    = (const int*)d_in[21];
  const int* esrc   = (const int*)d_in[22];
  const int* edst   = (const int*)d_in[23];

  float* wsf = (float*)d_ws;
  float* msum   = wsf;  wsf += (size_t)Bc * Nc * Hc;
  float* pa     = wsf;  wsf += (size_t)Bc * Nc * 3;
  float* pb_    = wsf;  wsf += (size_t)Bc * Nc * 3;
  float* deginv = wsf;  wsf += (size_t)NBc * Nc;
  _Float16* h16 = (_Float16*)wsf;
  _Float16* W1f = h16 + (size_t)Bc * Nc * Hc;
  _Float16* W2f = W1f + 196608;
  _Float16* P1f = W2f + 98304;
  _Float16* U1f = P1f + 98304;
  _Float16* U2f = U1f + 65536;
  int* hist   = (int*)(U2f + 32768);
  int* cursor = hist + NBc * Nc;
  int* offs   = cursor + NBc * Nc;
  int* sorted = offs + NBc * Nc;

  // --- sort edges by dst (once per call; hist doubles as degree) ---
  zero4_kernel<<<dim3((2 * NBc * Nc / 4 + 255) / 256), dim3(256), 0, stream>>>((float*)hist, 2 * NBc * Nc / 4);
  hist_kernel<<<dim3((NBc * Ec + 255) / 256), dim3(256), 0, stream>>>(hist, edst);
  scan_kernel<<<dim3(NBc), dim3(256), 0, stream>>>(hist, offs, deginv);
  sort_scatter_kernel<<<dim3((NBc * Ec + 255) / 256), dim3(256), 0, stream>>>(sorted, cursor, offs, edst);

  // --- weight fragment conversions ---
  conv_frag_kernel<<<dim3(768), dim3(256), 0, stream>>>(W1f, mW1, 16, 196608, 257L * 128);
  conv_frag_kernel<<<dim3(384), dim3(256), 0, stream>>>(W2f, mW2, 8, 98304, 128L * 128);
  conv_frag_kernel<<<dim3(384), dim3(256), 0, stream>>>(P1f, pW1, 8, 98304, 128L * 128);
  conv_frag_kernel<<<dim3(256), dim3(256), 0, stream>>>(U1f, uW1, 16, 65536, 256L * 128);
  conv_frag_kernel<<<dim3(128), dim3(256), 0, stream>>>(U2f, uW2, 8, 32768, 128L * 128);

  init_h_kernel<<<dim3((Bc * Nc * Hc + 255) / 256), dim3(256), 0, stream>>>(h16, bfe, x, Win, b_in, ent);
  init_p_kernel<<<dim3((Bc * Nc * 3 + 255) / 256), dim3(256), 0, stream>>>(pa, bp);

  float* pcur = pa;
  float* pnew = pb_;
  const int nmh = Bc * Nc * Hc;
  for (int l = 0; l < Lc; ++l) {
    zero4_kernel<<<dim3((nmh / 4 + 255) / 256), dim3(256), 0, stream>>>(msum, nmh / 4);
    copy_kernel<<<dim3((Bc * Nc * 3 + 255) / 256), dim3(256), 0, stream>>>(pnew, pcur, Bc * Nc * 3);
    edge_mfma_kernel<<<dim3(Bc * EB, NBc), dim3(256), 0, stream>>>(
        h16, pcur, msum, pnew, deginv, esrc, edst, sorted,
        W1f, W2f, P1f, mW1, mb1, mb2, pb1, pW2, pb2, l);
    update_mfma_kernel<<<dim3(Bc * Nc / 32), dim3(256), 0, stream>>>(h16, msum, U1f, U2f, ub1, ub2, l);
    float* t = pcur; pcur = pnew; pnew = t;
  }
  readout_kernel<<<dim3(1), dim3(256), 0, stream>>>(h16, ent, oW1, ob1, oW2, ob2, (float*)d_out);
}

// Round 5
// 695.693 us; speedup vs baseline: 5.3105x; 1.0378x over previous
//
#include <hip/hip_runtime.h>
#include <hip/hip_bf16.h>
#include <math.h>

#define Bc   2
#define Nc   10000
#define Ec   100000
#define Hc   128
#define DINc 8
#define DBc  16
#define NBc  3
#define Lc   2
#define EB   3125   // Ec/32 blocks per batch element

typedef float v4 __attribute__((ext_vector_type(4)));
typedef float f32x16 __attribute__((ext_vector_type(16)));
typedef _Float16 h8 __attribute__((ext_vector_type(8)));
typedef _Float16 h4 __attribute__((ext_vector_type(4)));

__device__ __forceinline__ float silu_f(float x) { return x / (1.f + __expf(-x)); }

// ---------------- small utility kernels ----------------

__global__ void zero4_kernel(float* __restrict__ p, int n4) {
  int i = blockIdx.x * blockDim.x + threadIdx.x;
  if (i < n4) ((v4*)p)[i] = (v4)(0.f);
}

__global__ void copy_kernel(float* __restrict__ dst, const float* __restrict__ src, int n) {
  int i = blockIdx.x * blockDim.x + threadIdx.x;
  if (i < n) dst[i] = src[i];
}

// ---------------- sort-by-dst machinery (edge lists are constant inputs) ----------------

__global__ void hist_kernel(int* __restrict__ hist, const int* __restrict__ edst) {
  int i = blockIdx.x * blockDim.x + threadIdx.x;
  if (i < NBc * Ec) {
    int k = i / Ec;
    atomicAdd(&hist[k * Nc + edst[i]], 1);
  }
}

__global__ void scan_kernel(const int* __restrict__ hist, int* __restrict__ offs,
                            float* __restrict__ deginv) {
  const int k = blockIdx.x, tid = threadIdx.x;
  const int NPT = 40;
  __shared__ int part[256];
  int local[NPT];
  int sum = 0;
  for (int j = 0; j < NPT; ++j) {
    int n = tid * NPT + j;
    if (n < Nc) { local[j] = sum; sum += hist[k * Nc + n]; }
  }
  part[tid] = sum;
  __syncthreads();
  for (int off = 1; off < 256; off <<= 1) {
    int v = (tid >= off) ? part[tid - off] : 0;
    __syncthreads();
    part[tid] += v;
    __syncthreads();
  }
  int excl = part[tid] - sum;
  for (int j = 0; j < NPT; ++j) {
    int n = tid * NPT + j;
    if (n < Nc) {
      offs[k * Nc + n] = excl + local[j];
      deginv[k * Nc + n] = 1.f / fmaxf((float)hist[k * Nc + n], 1.f);
    }
  }
}

__global__ void sort_scatter_kernel(int* __restrict__ sorted, int* __restrict__ cursor,
                                    const int* __restrict__ offs, const int* __restrict__ edst) {
  int i = blockIdx.x * blockDim.x + threadIdx.x;
  if (i < NBc * Ec) {
    int k = i / Ec, e = i - k * Ec;
    int d = edst[i];
    int pos = offs[k * Nc + d] + atomicAdd(&cursor[k * Nc + d], 1);
    sorted[k * Ec + pos] = e;
  }
}

// ---------------- init kernels ----------------

__global__ void init_h_kernel(_Float16* __restrict__ h16, const float* __restrict__ bfeat,
                              const float* __restrict__ x, const float* __restrict__ Win,
                              const float* __restrict__ b_in, const int* __restrict__ ent) {
  int g = blockIdx.x * blockDim.x + threadIdx.x;
  if (g >= Bc * Nc * Hc) return;
  int j = g & (Hc - 1);
  int bn = g >> 7;
  int n = bn % Nc;
  int b = bn / Nc;
  float acc = b_in[j];
#pragma unroll
  for (int i = 0; i < DBc; ++i) acc = fmaf(bfeat[n * DBc + i], Win[i * Hc + j], acc);
  if (n == ent[b]) {
#pragma unroll
    for (int i = 0; i < DINc; ++i) acc = fmaf(x[b * DINc + i], Win[(DBc + i) * Hc + j], acc);
  }
  h16[g] = (_Float16)acc;
}

__global__ void init_p_kernel(float* __restrict__ p, const float* __restrict__ bp) {
  int i = blockIdx.x * blockDim.x + threadIdx.x;
  if (i < Bc * Nc * 3) p[i] = bp[i % (Nc * 3)];
}

// ---------------- weight -> f16 MFMA-fragment-order conversion ----------------
// frag[lane, t, j] = src[kk = t*16 + (lane>>5)*8 + j][col = wave*32 + (lane&31)]
__global__ void conv_frag_kernel(_Float16* __restrict__ dst, const float* __restrict__ src,
                                 int nchunk, int total, long srcStride) {
  int g = blockIdx.x * blockDim.x + threadIdx.x;
  if (g >= total) return;
  int j = g & 7;
  int lane = (g >> 3) & 63;
  int q = g >> 9;
  int t = q % nchunk;
  int q2 = q / nchunk;
  int wave = q2 & 3;
  int mat = q2 >> 2;
  int kk = t * 16 + (lane >> 5) * 8 + j;
  int col = wave * 32 + (lane & 31);
  dst[g] = (_Float16)src[(size_t)mat * srcStride + (size_t)kk * Hc + col];
}

// ---------------- fused edge MLP kernel (swapped-operand f16 MFMA, single Abuf) ----------------
// grid (Bc*EB, NBc), 256 threads = 4 waves; 32 sorted edges/block.
// Abuf rows 512B: [hd | hs] -> GEMM1 -> m1 overwrites hs region -> GEMM2 ->
// m2 overwrites hd region -> GEMM3 / scatter.  LDS ~20KB -> 8 blocks/CU.

__global__ __launch_bounds__(256, 8)
void edge_mfma_kernel(const _Float16* __restrict__ h16, const float* __restrict__ p,
                      float* __restrict__ m_sum, float* __restrict__ p_new,
                      const float* __restrict__ deginv,
                      const int* __restrict__ esrc, const int* __restrict__ edst,
                      const int* __restrict__ sorted,
                      const _Float16* __restrict__ W1f, const _Float16* __restrict__ W2f,
                      const _Float16* __restrict__ P1f,
                      const float* __restrict__ mW1, const float* __restrict__ mb1,
                      const float* __restrict__ mb2, const float* __restrict__ pb1,
                      const float* __restrict__ pW2, const float* __restrict__ pb2,
                      int l) {
  const int k = blockIdx.y, lk = l * NBc + k;
  const int b = (blockIdx.x >= EB) ? 1 : 0;
  const int pos0 = (blockIdx.x - b * EB) << 5;
  const int tid = threadIdx.x;
  const int wave = tid >> 6, lane = tid & 63;
  const int lrow = lane & 31, lhalf = lane >> 5;

  __shared__ __align__(16) _Float16 Abuf[32 * 256];
  __shared__ int shd[32], shs[32], sdi[32];
  __shared__ float sd2[32], sdinvs[32], srel[32][3], scoef[32];
  __shared__ float cw1[Hc], cb1[Hc], cb2[Hc], cpb1[Hc], cpw2[Hc];

  if (tid < Hc) {
    cw1[tid]  = mW1[((size_t)lk * 257 + 256) * Hc + tid];  // d2 row of W1
    cb1[tid]  = mb1[lk * Hc + tid];
    cb2[tid]  = mb2[lk * Hc + tid];
    cpb1[tid] = pb1[lk * Hc + tid];
    cpw2[tid] = pW2[lk * Hc + tid];
  }
  if (tid < 32) {
    int e = sorted[k * Ec + pos0 + tid];
    int si = esrc[k * Ec + e], di = edst[k * Ec + e];
    int nd = b * Nc + di, ns = b * Nc + si;
    const float* pd = &p[(size_t)nd * 3];
    const float* ps = &p[(size_t)ns * 3];
    float rx = pd[0] - ps[0], ry = pd[1] - ps[1], rz = pd[2] - ps[2];
    srel[tid][0] = rx; srel[tid][1] = ry; srel[tid][2] = rz;
    sd2[tid] = rx * rx + ry * ry + rz * rz;
    sdinvs[tid] = deginv[k * Nc + di];
    sdi[tid] = di;
    shd[tid] = nd * Hc; shs[tid] = ns * Hc;
    scoef[tid] = 0.f;
  }
  __syncthreads();

  // gather h16 rows -> Abuf (16B chunks, XOR swizzle byte^=(row&7)<<4)
  {
    const int i = tid >> 3, c = tid & 7;
    const int sw = (i & 7) << 4;
    char* ab = (char*)Abuf;
    h8 v0 = *(const h8*)&h16[shd[i] + c * 8];
    h8 v1 = *(const h8*)&h16[shd[i] + 64 + c * 8];
    h8 v2 = *(const h8*)&h16[shs[i] + c * 8];
    h8 v3 = *(const h8*)&h16[shs[i] + 64 + c * 8];
    *(h8*)(ab + (i << 9) + ((c * 16) ^ sw)) = v0;
    *(h8*)(ab + (i << 9) + 128 + ((c * 16) ^ sw)) = v1;
    *(h8*)(ab + (i << 9) + 256 + ((c * 16) ^ sw)) = v2;
    *(h8*)(ab + (i << 9) + 384 + ((c * 16) ^ sw)) = v3;
  }
  __syncthreads();

  const int swz = (lrow & 7) << 4;
  const char* abc = (const char*)Abuf;
  char* abw = (char*)Abuf;

  // ---- GEMM1^T: m1^T = W1^T @ [hd|hs]^T  (K=256 over both halves) ----
  f32x16 acc;
#pragma unroll
  for (int r = 0; r < 16; ++r) acc[r] = 0.f;
#pragma unroll
  for (int t = 0; t < 16; ++t) {
    int off = (t << 5) + (lhalf << 4);          // 0..496
    h8 bact = *(const h8*)(abc + (lrow << 9) + ((off & 0x180)) + ((off & 0x70) ^ swz));
    h8 aw = *(const h8*)&W1f[((((size_t)lk * 4 + wave) * 16 + t) << 9) + (lane << 3)];
    acc = __builtin_amdgcn_mfma_f32_32x32x16_f16(aw, bact, acc, 0, 0, 0);
  }
  // m1 in registers
  h4 m1pk[4];
  {
    float d2e = sd2[lrow];
#pragma unroll
    for (int c = 0; c < 4; ++c) {
      int hb = (wave << 5) + (c << 3) + (lhalf << 2);
#pragma unroll
      for (int z = 0; z < 4; ++z)
        m1pk[c][z] = (_Float16)silu_f(acc[c * 4 + z] + d2e * cw1[hb + z] + cb1[hb + z]);
    }
  }
  __syncthreads();   // drain all GEMM1 reads of hs before overwriting
  {
#pragma unroll
    for (int c = 0; c < 4; ++c) {
      int hb = (wave << 5) + (c << 3) + (lhalf << 2);
      *(h4*)(abw + (lrow << 9) + 256 + (((hb << 1)) ^ swz)) = m1pk[c];   // m1 -> hs region
    }
  }
  __syncthreads();

  // ---- GEMM2^T: m2^T = W2^T @ m1^T ----
  f32x16 acc2;
#pragma unroll
  for (int r = 0; r < 16; ++r) acc2[r] = 0.f;
#pragma unroll
  for (int t = 0; t < 8; ++t) {
    h8 bact = *(const h8*)(abc + (lrow << 9) + 256 + ((((t << 5) + (lhalf << 4))) ^ swz));
    h8 aw = *(const h8*)&W2f[((((size_t)lk * 4 + wave) * 8 + t) << 9) + (lane << 3)];
    acc2 = __builtin_amdgcn_mfma_f32_32x32x16_f16(aw, bact, acc2, 0, 0, 0);
  }
  {
    // m2 -> hd region (bytes 0..255): disjoint from m1 region still being read
#pragma unroll
    for (int c = 0; c < 4; ++c) {
      int hb = (wave << 5) + (c << 3) + (lhalf << 2);
      h4 pk;
#pragma unroll
      for (int z = 0; z < 4; ++z)
        pk[z] = (_Float16)silu_f(acc2[c * 4 + z] + cb2[hb + z]);
      *(h4*)(abw + (lrow << 9) + (((hb << 1)) ^ swz)) = pk;
    }
  }
  __syncthreads();

  // ---- GEMM3^T: q^T = P1^T @ m2^T; coef = sum_h silu(q)*pW2 (lane-local) ----
  f32x16 acc3;
#pragma unroll
  for (int r = 0; r < 16; ++r) acc3[r] = 0.f;
#pragma unroll
  for (int t = 0; t < 8; ++t) {
    h8 bact = *(const h8*)(abc + (lrow << 9) + ((((t << 5) + (lhalf << 4))) ^ swz));
    h8 aw = *(const h8*)&P1f[((((size_t)lk * 4 + wave) * 8 + t) << 9) + (lane << 3)];
    acc3 = __builtin_amdgcn_mfma_f32_32x32x16_f16(aw, bact, acc3, 0, 0, 0);
  }
  {
    float csum = 0.f;
#pragma unroll
    for (int r = 0; r < 16; ++r) {
      int hg = (wave << 5) + (r & 3) + (((r >> 2)) << 3) + (lhalf << 2);
      csum += silu_f(acc3[r] + cpb1[hg]) * cpw2[hg];
    }
    csum += __shfl_down(csum, 32);
    if (lane < 32) atomicAdd(&scoef[lrow], csum);
  }
  __syncthreads();

  // ---- segmented m_sum scatter: rows sorted by dst within the block ----
  {
    const int col = tid & 127;
    const int r0 = (tid >> 7) << 4;     // 0 or 16
    const size_t bbase = (size_t)b * Nc * Hc;
    float accv = 0.f, cinv = 0.f;
    int cur = -1;
    for (int r = r0; r < r0 + 16; ++r) {   // dst uniform across lanes -> no divergence
      float v = (float)*(const _Float16*)(abc + (r << 9) + (((col << 1)) ^ ((r & 7) << 4)));
      int d = sdi[r];
      if (d != cur) {
        if (cur >= 0) atomicAdd(&m_sum[bbase + (size_t)cur * Hc + col], accv * cinv);
        cur = d; cinv = sdinvs[r]; accv = v;
      } else accv += v;
    }
    atomicAdd(&m_sum[bbase + (size_t)cur * Hc + col], accv * cinv);
  }
  // ---- p_new scatter ----
  if (tid < 32) {
    float cf = (scoef[tid] + pb2[lk]) * sdinvs[tid];
    float* pp = &p_new[((size_t)(b * Nc + sdi[tid])) * 3];
    atomicAdd(&pp[0], srel[tid][0] * cf);
    atomicAdd(&pp[1], srel[tid][1] * cf);
    atomicAdd(&pp[2], srel[tid][2] * cf);
  }
}

// ---------------- node update kernel (swapped-operand f16 MFMA, single Abuf) ----------------

__global__ __launch_bounds__(256, 8)
void update_mfma_kernel(_Float16* __restrict__ h16, const float* __restrict__ m_sum,
                        const _Float16* __restrict__ U1f, const _Float16* __restrict__ U2f,
                        const float* __restrict__ ub1, const float* __restrict__ ub2, int l) {
  const int tid = threadIdx.x;
  const int wave = tid >> 6, lane = tid & 63;
  const int lrow = lane & 31, lhalf = lane >> 5;
  const int row0 = blockIdx.x << 5;

  __shared__ __align__(16) _Float16 Abuf[32 * 256];
  __shared__ float cu1[Hc], cu2[Hc];

  if (tid < Hc) { cu1[tid] = ub1[l * Hc + tid]; cu2[tid] = ub2[l * Hc + tid]; }

  {
    const int i = tid >> 3, c = tid & 7;
    const int sw = (i & 7) << 4;
    char* ab = (char*)Abuf;
    size_t hb = (size_t)(row0 + i) * Hc;
    h8 v0 = *(const h8*)&h16[hb + c * 8];
    h8 v1 = *(const h8*)&h16[hb + 64 + c * 8];
    *(h8*)(ab + (i << 9) + ((c * 16) ^ sw)) = v0;
    *(h8*)(ab + (i << 9) + 128 + ((c * 16) ^ sw)) = v1;
#pragma unroll
    for (int q = 0; q < 4; ++q) {
      v4 mv = *(const v4*)&m_sum[hb + c * 4 + q * 32];
      h4 mh;
#pragma unroll
      for (int z = 0; z < 4; ++z) mh[z] = (_Float16)mv[z];
      *(h4*)(ab + (i << 9) + 256 + ((q * 64 + c * 8) ^ sw)) = mh;
    }
  }
  __syncthreads();

  const int swz = (lrow & 7) << 4;
  const char* abc = (const char*)Abuf;
  char* abw = (char*)Abuf;

  f32x16 acc;
#pragma unroll
  for (int r = 0; r < 16; ++r) acc[r] = 0.f;
#pragma unroll
  for (int t = 0; t < 16; ++t) {
    int off = (t << 5) + (lhalf << 4);
    h8 bact = *(const h8*)(abc + (lrow << 9) + ((off & 0x180)) + ((off & 0x70) ^ swz));
    h8 aw = *(const h8*)&U1f[((((size_t)l * 4 + wave) * 16 + t) << 9) + (lane << 3)];
    acc = __builtin_amdgcn_mfma_f32_32x32x16_f16(aw, bact, acc, 0, 0, 0);
  }
  h4 u1pk[4];
  {
#pragma unroll
    for (int c = 0; c < 4; ++c) {
      int hb = (wave << 5) + (c << 3) + (lhalf << 2);
#pragma unroll
      for (int z = 0; z < 4; ++z)
        u1pk[c][z] = (_Float16)silu_f(acc[c * 4 + z] + cu1[hb + z]);
    }
  }
  __syncthreads();
  {
#pragma unroll
    for (int c = 0; c < 4; ++c) {
      int hb = (wave << 5) + (c << 3) + (lhalf << 2);
      *(h4*)(abw + (lrow << 9) + 256 + (((hb << 1)) ^ swz)) = u1pk[c];
    }
  }
  __syncthreads();

  f32x16 acc2;
#pragma unroll
  for (int r = 0; r < 16; ++r) acc2[r] = 0.f;
#pragma unroll
  for (int t = 0; t < 8; ++t) {
    h8 bact = *(const h8*)(abc + (lrow << 9) + 256 + ((((t << 5) + (lhalf << 4))) ^ swz));
    h8 aw = *(const h8*)&U2f[((((size_t)l * 4 + wave) * 8 + t) << 9) + (lane << 3)];
    acc2 = __builtin_amdgcn_mfma_f32_32x32x16_f16(aw, bact, acc2, 0, 0, 0);
  }
  {
    _Float16* hp = &h16[(size_t)(row0 + lrow) * Hc];
#pragma unroll
    for (int c = 0; c < 4; ++c) {
      int hb = (wave << 5) + (c << 3) + (lhalf << 2);
      h4 old = *(const h4*)&hp[hb];
      h4 nv;
#pragma unroll
      for (int z = 0; z < 4; ++z)
        nv[z] = (_Float16)((float)old[z] + acc2[c * 4 + z] + cu2[hb + z]);
      *(h4*)&hp[hb] = nv;            // rows exclusive to block, chunks disjoint
    }
  }
}

// ---------------- readout ----------------

__global__ void readout_kernel(const _Float16* __restrict__ h16, const int* __restrict__ ent,
                               const float* __restrict__ oW1, const float* __restrict__ ob1,
                               const float* __restrict__ oW2, const float* __restrict__ ob2,
                               float* __restrict__ out) {
  __shared__ float tb[Bc][Hc];
  int tid = threadIdx.x;
  int b = tid >> 7, j = tid & 127;
  const _Float16* e = &h16[((size_t)(b * Nc + ent[b])) * Hc];
  float a = ob1[j];
#pragma unroll 4
  for (int i = 0; i < Hc; ++i) a = fmaf((float)e[i], oW1[i * Hc + j], a);
  tb[b][j] = silu_f(a);
  __syncthreads();
  if (tid < Bc) {
    float s = ob2[0];
    for (int i = 0; i < Hc; ++i) s = fmaf(tb[tid][i], oW2[i], s);
    out[tid] = s;
  }
}

// ---------------- host launcher ----------------

extern "C" void kernel_launch(void* const* d_in, const int* in_sizes, int n_in,
                              void* d_out, int out_size, void* d_ws, size_t ws_size,
                              hipStream_t stream) {
  const float* x    = (const float*)d_in[0];
  const float* bfe  = (const float*)d_in[1];
  const float* bp   = (const float*)d_in[2];
  const float* Win  = (const float*)d_in[3];
  const float* b_in = (const float*)d_in[4];
  const float* mW1  = (const float*)d_in[5];
  const float* mb1  = (const float*)d_in[6];
  const float* mW2  = (const float*)d_in[7];
  const float* mb2  = (const float*)d_in[8];
  const float* pW1  = (const float*)d_in[9];
  const float* pb1  = (const float*)d_in[10];
  const float* pW2  = (const float*)d_in[11];
  const float* pb2  = (const float*)d_in[12];
  const float* uW1  = (const float*)d_in[13];
  const float* ub1  = (const float*)d_in[14];
  const float* uW2  = (const float*)d_in[15];
  const float* ub2  = (const float*)d_in[16];
  const float* oW1  = (const float*)d_in[17];
  const float* ob1  = (const float*)d_in[18];
  const float* oW2  = (const float*)d_in[19];
  const float* ob2  = (const float*)d_in[20];
  const int* ent    = (const int*)d_in[21];
  const int* esrc   = (const int*)d_in[22];
  const int* edst   = (const int*)d_in[23];

  float* wsf = (float*)d_ws;
  float* msum   = wsf;  wsf += (size_t)Bc * Nc * Hc;
  float* pa     = wsf;  wsf += (size_t)Bc * Nc * 3;
  float* pb_    = wsf;  wsf += (size_t)Bc * Nc * 3;
  float* deginv = wsf;  wsf += (size_t)NBc * Nc;
  _Float16* h16 = (_Float16*)wsf;
  _Float16* W1f = h16 + (size_t)Bc * Nc * Hc;
  _Float16* W2f = W1f + 196608;
  _Float16* P1f = W2f + 98304;
  _Float16* U1f = P1f + 98304;
  _Float16* U2f = U1f + 65536;
  int* hist   = (int*)(U2f + 32768);
  int* cursor = hist + NBc * Nc;
  int* offs   = cursor + NBc * Nc;
  int* sorted = offs + NBc * Nc;

  // --- sort edges by dst (once per call; hist doubles as degree) ---
  zero4_kernel<<<dim3((2 * NBc * Nc / 4 + 255) / 256), dim3(256), 0, stream>>>((float*)hist, 2 * NBc * Nc / 4);
  hist_kernel<<<dim3((NBc * Ec + 255) / 256), dim3(256), 0, stream>>>(hist, edst);
  scan_kernel<<<dim3(NBc), dim3(256), 0, stream>>>(hist, offs, deginv);
  sort_scatter_kernel<<<dim3((NBc * Ec + 255) / 256), dim3(256), 0, stream>>>(sorted, cursor, offs, edst);

  // --- weight fragment conversions ---
  conv_frag_kernel<<<dim3(768), dim3(256), 0, stream>>>(W1f, mW1, 16, 196608, 257L * 128);
  conv_frag_kernel<<<dim3(384), dim3(256), 0, stream>>>(W2f, mW2, 8, 98304, 128L * 128);
  conv_frag_kernel<<<dim3(384), dim3(256), 0, stream>>>(P1f, pW1, 8, 98304, 128L * 128);
  conv_frag_kernel<<<dim3(256), dim3(256), 0, stream>>>(U1f, uW1, 16, 65536, 256L * 128);
  conv_frag_kernel<<<dim3(128), dim3(256), 0, stream>>>(U2f, uW2, 8, 32768, 128L * 128);

  init_h_kernel<<<dim3((Bc * Nc * Hc + 255) / 256), dim3(256), 0, stream>>>(h16, bfe, x, Win, b_in, ent);
  init_p_kernel<<<dim3((Bc * Nc * 3 + 255) / 256), dim3(256), 0, stream>>>(pa, bp);

  float* pcur = pa;
  float* pnew = pb_;
  const int nmh = Bc * Nc * Hc;
  for (int l = 0; l < Lc; ++l) {
    zero4_kernel<<<dim3((nmh / 4 + 255) / 256), dim3(256), 0, stream>>>(msum, nmh / 4);
    copy_kernel<<<dim3((Bc * Nc * 3 + 255) / 256), dim3(256), 0, stream>>>(pnew, pcur, Bc * Nc * 3);
    edge_mfma_kernel<<<dim3(Bc * EB, NBc), dim3(256), 0, stream>>>(
        h16, pcur, msum, pnew, deginv, esrc, edst, sorted,
        W1f, W2f, P1f, mW1, mb1, mb2, pb1, pW2, pb2, l);
    update_mfma_kernel<<<dim3(Bc * Nc / 32), dim3(256), 0, stream>>>(h16, msum, U1f, U2f, ub1, ub2, l);
    float* t = pcur; pcur = pnew; pnew = t;
  }
  readout_kernel<<<dim3(1), dim3(256), 0, stream>>>(h16, ent, oW1, ob1, oW2, ob2, (float*)d_out);
}

// Round 8
// 672.149 us; speedup vs baseline: 5.4965x; 1.0350x over previous
//
#include <hip/hip_runtime.h>
#include <hip/hip_bf16.h>
#include <math.h>

#define Bc   2
#define Nc   10000
#define Ec   100000
#define Hc   128
#define DINc 8
#define DBc  16
#define NBc  3
#define Lc   2
#define EB   3125   // Ec/32 blocks per batch element

typedef float v4 __attribute__((ext_vector_type(4)));
typedef float f32x16 __attribute__((ext_vector_type(16)));
typedef _Float16 h8 __attribute__((ext_vector_type(8)));
typedef _Float16 h4 __attribute__((ext_vector_type(4)));

__device__ __forceinline__ float silu_f(float x) {
  return x * __builtin_amdgcn_rcpf(1.f + __expf(-x));   // raw v_rcp: skip div fixup
}

__device__ __forceinline__ h4 pack4(float a, float b, float c, float d) {
  typedef decltype(__builtin_amdgcn_cvt_pkrtz(0.f, 0.f)) pk2;
  union { h4 v; pk2 p[2]; } u;
  u.p[0] = __builtin_amdgcn_cvt_pkrtz(a, b);
  u.p[1] = __builtin_amdgcn_cvt_pkrtz(c, d);
  return u.v;
}

// ---------------- small utility kernels ----------------

__global__ void zero4_kernel(float* __restrict__ p, int n4) {
  int i = blockIdx.x * blockDim.x + threadIdx.x;
  if (i < n4) ((v4*)p)[i] = (v4)(0.f);
}

__global__ void copy_kernel(float* __restrict__ dst, const float* __restrict__ src, int n) {
  int i = blockIdx.x * blockDim.x + threadIdx.x;
  if (i < n) dst[i] = src[i];
}

// ---------------- sort-by-dst machinery (edge lists are constant inputs) ----------------

__global__ void hist_kernel(int* __restrict__ hist, const int* __restrict__ edst) {
  int i = blockIdx.x * blockDim.x + threadIdx.x;
  if (i < NBc * Ec) {
    int k = i / Ec;
    atomicAdd(&hist[k * Nc + edst[i]], 1);
  }
}

__global__ void scan_kernel(const int* __restrict__ hist, int* __restrict__ offs,
                            float* __restrict__ deginv) {
  const int k = blockIdx.x, tid = threadIdx.x;
  const int NPT = 40;
  __shared__ int part[256];
  int local[NPT];
  int sum = 0;
  for (int j = 0; j < NPT; ++j) {
    int n = tid * NPT + j;
    if (n < Nc) { local[j] = sum; sum += hist[k * Nc + n]; }
  }
  part[tid] = sum;
  __syncthreads();
  for (int off = 1; off < 256; off <<= 1) {
    int v = (tid >= off) ? part[tid - off] : 0;
    __syncthreads();
    part[tid] += v;
    __syncthreads();
  }
  int excl = part[tid] - sum;
  for (int j = 0; j < NPT; ++j) {
    int n = tid * NPT + j;
    if (n < Nc) {
      offs[k * Nc + n] = excl + local[j];
      deginv[k * Nc + n] = 1.f / fmaxf((float)hist[k * Nc + n], 1.f);
    }
  }
}

__global__ void sort_scatter_kernel(int* __restrict__ sorted, int* __restrict__ cursor,
                                    const int* __restrict__ offs, const int* __restrict__ edst) {
  int i = blockIdx.x * blockDim.x + threadIdx.x;
  if (i < NBc * Ec) {
    int k = i / Ec, e = i - k * Ec;
    int d = edst[i];
    int pos = offs[k * Nc + d] + atomicAdd(&cursor[k * Nc + d], 1);
    sorted[k * Ec + pos] = e;
  }
}

// ---------------- init kernels ----------------

__global__ void init_h_kernel(_Float16* __restrict__ h16, const float* __restrict__ bfeat,
                              const float* __restrict__ x, const float* __restrict__ Win,
                              const float* __restrict__ b_in, const int* __restrict__ ent) {
  int g = blockIdx.x * blockDim.x + threadIdx.x;
  if (g >= Bc * Nc * Hc) return;
  int j = g & (Hc - 1);
  int bn = g >> 7;
  int n = bn % Nc;
  int b = bn / Nc;
  float acc = b_in[j];
#pragma unroll
  for (int i = 0; i < DBc; ++i) acc = fmaf(bfeat[n * DBc + i], Win[i * Hc + j], acc);
  if (n == ent[b]) {
#pragma unroll
    for (int i = 0; i < DINc; ++i) acc = fmaf(x[b * DINc + i], Win[(DBc + i) * Hc + j], acc);
  }
  h16[g] = (_Float16)acc;
}

__global__ void init_p_kernel(float* __restrict__ p, const float* __restrict__ bp) {
  int i = blockIdx.x * blockDim.x + threadIdx.x;
  if (i < Bc * Nc * 3) p[i] = bp[i % (Nc * 3)];
}

// ---------------- weight -> extended f16 MFMA-fragment conversion ----------------
// dst[((mat*4+wave)*nchunk + t)*512 + lane*8 + j]:
//   kk = t*16 + (lane>>5)*8 + j, col = wave*32 + (lane&31)
//   kk < realRows -> src[mat][kk][col]; kk == biasRow -> bias[mat][col]; else 0.
__global__ void conv_ext_kernel(_Float16* __restrict__ dst, const float* __restrict__ src,
                                const float* __restrict__ bias,
                                int nchunk, int total, int realRows, int biasRow) {
  int g = blockIdx.x * blockDim.x + threadIdx.x;
  if (g >= total) return;
  int j = g & 7;
  int lane = (g >> 3) & 63;
  int q = g >> 9;
  int t = q % nchunk;
  int q2 = q / nchunk;
  int wave = q2 & 3;
  int mat = q2 >> 2;
  int kk = t * 16 + (lane >> 5) * 8 + j;
  int col = (wave << 5) + (lane & 31);
  float v = 0.f;
  if (kk < realRows)      v = src[((size_t)mat * realRows + kk) * Hc + col];
  else if (kk == biasRow) v = bias[mat * Hc + col];
  dst[g] = (_Float16)v;
}

// ---------------- fused edge MLP kernel ----------------
// grid (Bc*EB, NBc), 256 threads = 4 waves; 32 sorted edges/block.
// All LDS activation buffers in MFMA B-frag order: chunk t at t*1024B, lane reads
// lane*16B + imm offset (conflict-free, zero addr VALU). Biases/d2 folded into
// an extra K=16 chunk (Dchk). m2 dual-stored (frag + swizzled row-major) for scatter.

__global__ __launch_bounds__(256, 8)
void edge_mfma_kernel(const _Float16* __restrict__ h16, const float* __restrict__ p,
                      float* __restrict__ m_sum, float* __restrict__ p_new,
                      const float* __restrict__ deginv,
                      const int* __restrict__ esrc, const int* __restrict__ edst,
                      const int* __restrict__ sorted,
                      const _Float16* __restrict__ W1e, const _Float16* __restrict__ W2e,
                      const _Float16* __restrict__ P1e,
                      const float* __restrict__ pW2, const float* __restrict__ pb2,
                      int l) {
  const int k = blockIdx.y, lk = l * NBc + k;
  const int b = (blockIdx.x >= EB) ? 1 : 0;
  const int pos0 = (blockIdx.x - b * EB) << 5;
  const int tid = threadIdx.x;
  const int wave = tid >> 6, lane = tid & 63;
  const int lrow = lane & 31, lhalf = lane >> 5;

  __shared__ __align__(16) _Float16 RegA[16 * 512];  // 16 chunks: [hd|hs] -> m1(0..7) -> m2frag(8..15)/m2rowmajor(0..7)
  __shared__ __align__(16) _Float16 Dchk[512];       // k-ext chunk: [d2, 1, 0...] per edge
  __shared__ int shd[32], shs[32], sdi[32];
  __shared__ float sdinvs[32], srel[32][3], scoef[32];
  __shared__ float cpw2[Hc];
  __shared__ unsigned sflush;

  if (tid < Hc) cpw2[tid] = pW2[lk * Hc + tid];
  if (tid < 32) {
    int e = sorted[k * Ec + pos0 + tid];
    int si = esrc[k * Ec + e], di = edst[k * Ec + e];
    int nd = b * Nc + di, ns = b * Nc + si;
    const float* pd = &p[(size_t)nd * 3];
    const float* ps = &p[(size_t)ns * 3];
    float rx = pd[0] - ps[0], ry = pd[1] - ps[1], rz = pd[2] - ps[2];
    srel[tid][0] = rx; srel[tid][1] = ry; srel[tid][2] = rz;
    float d2 = rx * rx + ry * ry + rz * rz;
    sdinvs[tid] = deginv[k * Nc + di];
    sdi[tid] = di;
    shd[tid] = nd * Hc; shs[tid] = ns * Hc;
    scoef[tid] = 0.f;
    h8 dv = (h8)(_Float16)0.f;
    dv[0] = (_Float16)d2; dv[1] = (_Float16)1.f;
    *(h8*)&Dchk[tid * 8] = dv;
    // segment detection (rows sorted by dst)
    int prev = __shfl_up(di, 1);
    bool isStart = (tid == 0) || (di != prev);
    unsigned long long m = __ballot(isStart);
    if (tid == 0) sflush = (unsigned)((m >> 1) | 0x80000000ull);
  } else if (tid < 64) {
    h8 dv = (h8)(_Float16)0.f;
    *(h8*)&Dchk[tid * 8] = dv;
  }
  __syncthreads();

  // gather h16 rows directly into frag order
  {
    const int i = tid & 31, c = tid >> 5;     // edge i, chunk-col c (0..7)
    h8 v0 = *(const h8*)&h16[shd[i] + c * 8];
    h8 v1 = *(const h8*)&h16[shd[i] + 64 + c * 8];
    h8 v2 = *(const h8*)&h16[shs[i] + c * 8];
    h8 v3 = *(const h8*)&h16[shs[i] + 64 + c * 8];
    int slot = (i + ((c & 1) << 5)) << 3;     // (edge + 32*khalf)*8 halfs
    int tb = (c >> 1) << 9;                   // chunk*(512 halfs)
    *(h8*)&RegA[tb + 0 * 2048 + slot] = v0;   // k   0..63  -> t = c>>1
    *(h8*)&RegA[tb + 4 * 512  + slot] = v1;   // k  64..127 -> t = 4 + c>>1
    *(h8*)&RegA[tb + 8 * 512  + slot] = v2;   // k 128..191
    *(h8*)&RegA[tb + 12 * 512 + slot] = v3;   // k 192..255
  }
  __syncthreads();

  // ---- GEMM1^T: K=272 (256 act + Dchk), bias+d2 folded ----
  const _Float16* wb1 = &W1e[(size_t)(lk * 4 + wave) * (17 * 512)];
  f32x16 acc;
#pragma unroll
  for (int r = 0; r < 16; ++r) acc[r] = 0.f;
#pragma unroll
  for (int t = 0; t < 16; ++t) {
    h8 bact = *(const h8*)&RegA[t * 512 + lane * 8];
    h8 aw   = *(const h8*)&wb1[t * 512 + lane * 8];
    acc = __builtin_amdgcn_mfma_f32_32x32x16_f16(aw, bact, acc, 0, 0, 0);
  }
  {
    h8 bact = *(const h8*)&Dchk[lane * 8];
    h8 aw   = *(const h8*)&wb1[16 * 512 + lane * 8];
    acc = __builtin_amdgcn_mfma_f32_32x32x16_f16(aw, bact, acc, 0, 0, 0);
  }
  h4 m1pk[4];
#pragma unroll
  for (int c = 0; c < 4; ++c)
    m1pk[c] = pack4(silu_f(acc[c * 4 + 0]), silu_f(acc[c * 4 + 1]),
                    silu_f(acc[c * 4 + 2]), silu_f(acc[c * 4 + 3]));
  __syncthreads();   // all GEMM1 reads complete
  // m1 -> frag chunks 0..7 (col hb = wave*32 + c*8 + lhalf*4)
#pragma unroll
  for (int c = 0; c < 4; ++c) {
    int t = (wave << 1) + (c >> 1);
    int slot = lrow + ((c & 1) << 5);
    *(h4*)&RegA[t * 512 + slot * 8 + lhalf * 4] = m1pk[c];
  }
  __syncthreads();

  // ---- GEMM2^T: K=144 (128 m1 + Dchk bias slot) ----
  const _Float16* wb2 = &W2e[(size_t)(lk * 4 + wave) * (9 * 512)];
  f32x16 acc2;
#pragma unroll
  for (int r = 0; r < 16; ++r) acc2[r] = 0.f;
#pragma unroll
  for (int t = 0; t < 8; ++t) {
    h8 bact = *(const h8*)&RegA[t * 512 + lane * 8];
    h8 aw   = *(const h8*)&wb2[t * 512 + lane * 8];
    acc2 = __builtin_amdgcn_mfma_f32_32x32x16_f16(aw, bact, acc2, 0, 0, 0);
  }
  {
    h8 bact = *(const h8*)&Dchk[lane * 8];
    h8 aw   = *(const h8*)&wb2[8 * 512 + lane * 8];
    acc2 = __builtin_amdgcn_mfma_f32_32x32x16_f16(aw, bact, acc2, 0, 0, 0);
  }
  h4 m2pk[4];
#pragma unroll
  for (int c = 0; c < 4; ++c) {
    m2pk[c] = pack4(silu_f(acc2[c * 4 + 0]), silu_f(acc2[c * 4 + 1]),
                    silu_f(acc2[c * 4 + 2]), silu_f(acc2[c * 4 + 3]));
    int t = 8 + (wave << 1) + (c >> 1);
    int slot = lrow + ((c & 1) << 5);
    *(h4*)&RegA[t * 512 + slot * 8 + lhalf * 4] = m2pk[c];   // m2 frag -> chunks 8..15
  }
  __syncthreads();   // all GEMM2 m1-reads complete; m2 frag visible
  // m2 row-major (swizzled) -> chunks 0..7 region for the scatter
  {
    char* rm = (char*)RegA;
#pragma unroll
    for (int c = 0; c < 4; ++c) {
      int hb = (wave << 5) + (c << 3) + (lhalf << 2);
      *(h4*)(rm + (lrow << 8) + (((hb << 1)) ^ ((lrow & 15) << 4))) = m2pk[c];
    }
  }

  // ---- GEMM3^T: q = P1e([m2|1]) ; coef = sum silu(q)*pW2 (lane-local) ----
  const _Float16* wb3 = &P1e[(size_t)(lk * 4 + wave) * (9 * 512)];
  f32x16 acc3;
#pragma unroll
  for (int r = 0; r < 16; ++r) acc3[r] = 0.f;
#pragma unroll
  for (int t = 0; t < 8; ++t) {
    h8 bact = *(const h8*)&RegA[(8 + t) * 512 + lane * 8];
    h8 aw   = *(const h8*)&wb3[t * 512 + lane * 8];
    acc3 = __builtin_amdgcn_mfma_f32_32x32x16_f16(aw, bact, acc3, 0, 0, 0);
  }
  {
    h8 bact = *(const h8*)&Dchk[lane * 8];
    h8 aw   = *(const h8*)&wb3[8 * 512 + lane * 8];
    acc3 = __builtin_amdgcn_mfma_f32_32x32x16_f16(aw, bact, acc3, 0, 0, 0);
  }
  {
    float csum = 0.f;
#pragma unroll
    for (int r = 0; r < 16; ++r) {
      int hg = (wave << 5) + (r & 3) + ((r >> 2) << 3) + (lhalf << 2);
      csum += silu_f(acc3[r]) * cpw2[hg];
    }
    csum += __shfl_down(csum, 32);
    if (lane < 32) atomicAdd(&scoef[lrow], csum);
  }
  __syncthreads();   // rowmajor m2 + scoef complete

  // ---- segmented m_sum scatter (uniform flush-mask, no per-row compares) ----
  {
    const int col = tid & 127;
    const int r0 = (tid >> 7) << 4;     // 0 or 16 (wave-uniform)
    const size_t bbase = (size_t)b * Nc * Hc;
    const unsigned fm = sflush;
    const char* rm = (const char*)RegA;
    float accv = 0.f;
#pragma unroll
    for (int rr = 0; rr < 16; ++rr) {
      int r = r0 + rr;
      float v = (float)*(const _Float16*)(rm + (r << 8) + (((col << 1)) ^ ((r & 15) << 4)));
      accv += v;
      if ((fm >> r) & 1u) {
        atomicAdd(&m_sum[bbase + (size_t)sdi[r] * Hc + col], accv * sdinvs[r]);
        accv = 0.f;
      }
    }
    if (r0 == 0 && !((fm >> 15) & 1u))
      atomicAdd(&m_sum[bbase + (size_t)sdi[15] * Hc + col], accv * sdinvs[15]);
  }
  // ---- p_new scatter ----
  if (tid < 32) {
    float cf = (scoef[tid] + pb2[lk]) * sdinvs[tid];
    float* pp = &p_new[((size_t)(b * Nc + sdi[tid])) * 3];
    atomicAdd(&pp[0], srel[tid][0] * cf);
    atomicAdd(&pp[1], srel[tid][1] * cf);
    atomicAdd(&pp[2], srel[tid][2] * cf);
  }
}

// ---------------- node update kernel (same structure) ----------------

__global__ __launch_bounds__(256, 8)
void update_mfma_kernel(_Float16* __restrict__ h16, const float* __restrict__ m_sum,
                        const _Float16* __restrict__ U1e, const _Float16* __restrict__ U2e,
                        int l) {
  const int tid = threadIdx.x;
  const int wave = tid >> 6, lane = tid & 63;
  const int lrow = lane & 31, lhalf = lane >> 5;
  const int row0 = blockIdx.x << 5;

  __shared__ __align__(16) _Float16 RegA[16 * 512];
  __shared__ __align__(16) _Float16 Dchk[512];

  if (tid < 64) {
    h8 dv = (h8)(_Float16)0.f;
    if (tid < 32) dv[1] = (_Float16)1.f;
    *(h8*)&Dchk[tid * 8] = dv;
  }
  {
    const int i = tid & 31, c = tid >> 5;
    size_t hb = (size_t)(row0 + i) * Hc;
    h8 v0 = *(const h8*)&h16[hb + c * 8];
    h8 v1 = *(const h8*)&h16[hb + 64 + c * 8];
    v4 m0 = *(const v4*)&m_sum[hb + c * 8];
    v4 m1 = *(const v4*)&m_sum[hb + c * 8 + 4];
    v4 m2 = *(const v4*)&m_sum[hb + 64 + c * 8];
    v4 m3 = *(const v4*)&m_sum[hb + 64 + c * 8 + 4];
    union { h8 v; h4 q[2]; } w0, w1;
    w0.q[0] = pack4(m0[0], m0[1], m0[2], m0[3]);
    w0.q[1] = pack4(m1[0], m1[1], m1[2], m1[3]);
    w1.q[0] = pack4(m2[0], m2[1], m2[2], m2[3]);
    w1.q[1] = pack4(m3[0], m3[1], m3[2], m3[3]);
    int slot = (i + ((c & 1) << 5)) << 3;
    int tb = (c >> 1) << 9;
    *(h8*)&RegA[tb + slot] = v0;
    *(h8*)&RegA[tb + 4 * 512 + slot] = v1;
    *(h8*)&RegA[tb + 8 * 512 + slot] = w0.v;
    *(h8*)&RegA[tb + 12 * 512 + slot] = w1.v;
  }
  __syncthreads();

  const _Float16* wb1 = &U1e[(size_t)(l * 4 + wave) * (17 * 512)];
  f32x16 acc;
#pragma unroll
  for (int r = 0; r < 16; ++r) acc[r] = 0.f;
#pragma unroll
  for (int t = 0; t < 16; ++t) {
    h8 bact = *(const h8*)&RegA[t * 512 + lane * 8];
    h8 aw   = *(const h8*)&wb1[t * 512 + lane * 8];
    acc = __builtin_amdgcn_mfma_f32_32x32x16_f16(aw, bact, acc, 0, 0, 0);
  }
  {
    h8 bact = *(const h8*)&Dchk[lane * 8];
    h8 aw   = *(const h8*)&wb1[16 * 512 + lane * 8];
    acc = __builtin_amdgcn_mfma_f32_32x32x16_f16(aw, bact, acc, 0, 0, 0);
  }
  h4 u1pk[4];
#pragma unroll
  for (int c = 0; c < 4; ++c)
    u1pk[c] = pack4(silu_f(acc[c * 4 + 0]), silu_f(acc[c * 4 + 1]),
                    silu_f(acc[c * 4 + 2]), silu_f(acc[c * 4 + 3]));
  __syncthreads();
#pragma unroll
  for (int c = 0; c < 4; ++c) {
    int t = (wave << 1) + (c >> 1);
    int slot = lrow + ((c & 1) << 5);
    *(h4*)&RegA[t * 512 + slot * 8 + lhalf * 4] = u1pk[c];
  }
  __syncthreads();

  const _Float16* wb2 = &U2e[(size_t)(l * 4 + wave) * (9 * 512)];
  f32x16 acc2;
#pragma unroll
  for (int r = 0; r < 16; ++r) acc2[r] = 0.f;
#pragma unroll
  for (int t = 0; t < 8; ++t) {
    h8 bact = *(const h8*)&RegA[t * 512 + lane * 8];
    h8 aw   = *(const h8*)&wb2[t * 512 + lane * 8];
    acc2 = __builtin_amdgcn_mfma_f32_32x32x16_f16(aw, bact, acc2, 0, 0, 0);
  }
  {
    h8 bact = *(const h8*)&Dchk[lane * 8];
    h8 aw   = *(const h8*)&wb2[8 * 512 + lane * 8];
    acc2 = __builtin_amdgcn_mfma_f32_32x32x16_f16(aw, bact, acc2, 0, 0, 0);
  }
  {
    _Float16* hp = &h16[(size_t)(row0 + lrow) * Hc];
#pragma unroll
    for (int c = 0; c < 4; ++c) {
      int hb = (wave << 5) + (c << 3) + (lhalf << 2);
      h4 old = *(const h4*)&hp[hb];
      *(h4*)&hp[hb] = pack4((float)old[0] + acc2[c * 4 + 0], (float)old[1] + acc2[c * 4 + 1],
                            (float)old[2] + acc2[c * 4 + 2], (float)old[3] + acc2[c * 4 + 3]);
    }
  }
}

// ---------------- readout ----------------

__global__ void readout_kernel(const _Float16* __restrict__ h16, const int* __restrict__ ent,
                               const float* __restrict__ oW1, const float* __restrict__ ob1,
                               const float* __restrict__ oW2, const float* __restrict__ ob2,
                               float* __restrict__ out) {
  __shared__ float tb[Bc][Hc];
  int tid = threadIdx.x;
  int b = tid >> 7, j = tid & 127;
  const _Float16* e = &h16[((size_t)(b * Nc + ent[b])) * Hc];
  float a = ob1[j];
#pragma unroll 4
  for (int i = 0; i < Hc; ++i) a = fmaf((float)e[i], oW1[i * Hc + j], a);
  tb[b][j] = silu_f(a);
  __syncthreads();
  if (tid < Bc) {
    float s = ob2[0];
    for (int i = 0; i < Hc; ++i) s = fmaf(tb[tid][i], oW2[i], s);
    out[tid] = s;
  }
}

// ---------------- host launcher ----------------

extern "C" void kernel_launch(void* const* d_in, const int* in_sizes, int n_in,
                              void* d_out, int out_size, void* d_ws, size_t ws_size,
                              hipStream_t stream) {
  const float* x    = (const float*)d_in[0];
  const float* bfe  = (const float*)d_in[1];
  const float* bp   = (const float*)d_in[2];
  const float* Win  = (const float*)d_in[3];
  const float* b_in = (const float*)d_in[4];
  const float* mW1  = (const float*)d_in[5];
  const float* mb1  = (const float*)d_in[6];
  const float* mW2  = (const float*)d_in[7];
  const float* mb2  = (const float*)d_in[8];
  const float* pW1  = (const float*)d_in[9];
  const float* pb1  = (const float*)d_in[10];
  const float* pW2  = (const float*)d_in[11];
  const float* pb2  = (const float*)d_in[12];
  const float* uW1  = (const float*)d_in[13];
  const float* ub1  = (const float*)d_in[14];
  const float* uW2  = (const float*)d_in[15];
  const float* ub2  = (const float*)d_in[16];
  const float* oW1  = (const float*)d_in[17];
  const float* ob1  = (const float*)d_in[18];
  const float* oW2  = (const float*)d_in[19];
  const float* ob2  = (const float*)d_in[20];
  const int* ent    = (const int*)d_in[21];
  const int* esrc   = (const int*)d_in[22];
  const int* edst   = (const int*)d_in[23];

  float* wsf = (float*)d_ws;
  float* msum   = wsf;  wsf += (size_t)Bc * Nc * Hc;
  float* pa     = wsf;  wsf += (size_t)Bc * Nc * 3;
  float* pb_    = wsf;  wsf += (size_t)Bc * Nc * 3;
  float* deginv = wsf;  wsf += (size_t)NBc * Nc;
  _Float16* h16 = (_Float16*)wsf;
  _Float16* W1e = h16 + (size_t)Bc * Nc * Hc;
  _Float16* W2e = W1e + 208896;   // 6*4*17*512
  _Float16* P1e = W2e + 110592;   // 6*4*9*512
  _Float16* U1e = P1e + 110592;
  _Float16* U2e = U1e + 69632;    // 2*4*17*512
  int* hist   = (int*)(U2e + 36864);
  int* cursor = hist + NBc * Nc;
  int* offs   = cursor + NBc * Nc;
  int* sorted = offs + NBc * Nc;

  // --- sort edges by dst (once per call; hist doubles as degree) ---
  zero4_kernel<<<dim3((2 * NBc * Nc / 4 + 255) / 256), dim3(256), 0, stream>>>((float*)hist, 2 * NBc * Nc / 4);
  hist_kernel<<<dim3((NBc * Ec + 255) / 256), dim3(256), 0, stream>>>(hist, edst);
  scan_kernel<<<dim3(NBc), dim3(256), 0, stream>>>(hist, offs, deginv);
  sort_scatter_kernel<<<dim3((NBc * Ec + 255) / 256), dim3(256), 0, stream>>>(sorted, cursor, offs, edst);

  // --- extended weight fragment conversions (bias/d2 rows folded) ---
  conv_ext_kernel<<<dim3(816), dim3(256), 0, stream>>>(W1e, mW1, mb1, 17, 208896, 257, 257);
  conv_ext_kernel<<<dim3(432), dim3(256), 0, stream>>>(W2e, mW2, mb2, 9, 110592, 128, 129);
  conv_ext_kernel<<<dim3(432), dim3(256), 0, stream>>>(P1e, pW1, pb1, 9, 110592, 128, 129);
  conv_ext_kernel<<<dim3(272), dim3(256), 0, stream>>>(U1e, uW1, ub1, 17, 69632, 256, 257);
  conv_ext_kernel<<<dim3(144), dim3(256), 0, stream>>>(U2e, uW2, ub2, 9, 36864, 128, 129);

  init_h_kernel<<<dim3((Bc * Nc * Hc + 255) / 256), dim3(256), 0, stream>>>(h16, bfe, x, Win, b_in, ent);
  init_p_kernel<<<dim3((Bc * Nc * 3 + 255) / 256), dim3(256), 0, stream>>>(pa, bp);

  float* pcur = pa;
  float* pnew = pb_;
  const int nmh = Bc * Nc * Hc;
  for (int l = 0; l < Lc; ++l) {
    zero4_kernel<<<dim3((nmh / 4 + 255) / 256), dim3(256), 0, stream>>>(msum, nmh / 4);
    copy_kernel<<<dim3((Bc * Nc * 3 + 255) / 256), dim3(256), 0, stream>>>(pnew, pcur, Bc * Nc * 3);
    edge_mfma_kernel<<<dim3(Bc * EB, NBc), dim3(256), 0, stream>>>(
        h16, pcur, msum, pnew, deginv, esrc, edst, sorted,
        W1e, W2e, P1e, pW2, pb2, l);
    update_mfma_kernel<<<dim3(Bc * Nc / 32), dim3(256), 0, stream>>>(h16, msum, U1e, U2e, l);
    float* t = pcur; pcur = pnew; pnew = t;
  }
  readout_kernel<<<dim3(1), dim3(256), 0, stream>>>(h16, ent, oW1, ob1, oW2, ob2, (float*)d_out);
}

// Round 9
// 669.556 us; speedup vs baseline: 5.5178x; 1.0039x over previous
//
#include <hip/hip_runtime.h>
#include <hip/hip_bf16.h>
#include <math.h>

#define Bc   2
#define Nc   10000
#define Ec   100000
#define Hc   128
#define DINc 8
#define DBc  16
#define NBc  3
#define Lc   2

typedef float v4 __attribute__((ext_vector_type(4)));
typedef float f32x16 __attribute__((ext_vector_type(16)));
typedef _Float16 h8 __attribute__((ext_vector_type(8)));
typedef _Float16 h4 __attribute__((ext_vector_type(4)));

__device__ __forceinline__ float silu_f(float x) {
  return x * __builtin_amdgcn_rcpf(1.f + __expf(-x));
}

__device__ __forceinline__ h4 pack4(float a, float b, float c, float d) {
  typedef decltype(__builtin_amdgcn_cvt_pkrtz(0.f, 0.f)) pk2;
  union { h4 v; pk2 p[2]; } u;
  u.p[0] = __builtin_amdgcn_cvt_pkrtz(a, b);
  u.p[1] = __builtin_amdgcn_cvt_pkrtz(c, d);
  return u.v;
}

// ---------------- small utility kernels ----------------

__global__ void zero4_kernel(float* __restrict__ p, int n4) {
  int i = blockIdx.x * blockDim.x + threadIdx.x;
  if (i < n4) ((v4*)p)[i] = (v4)(0.f);
}

__global__ void copy_kernel(float* __restrict__ dst, const float* __restrict__ src, int n) {
  int i = blockIdx.x * blockDim.x + threadIdx.x;
  if (i < n) dst[i] = src[i];
}

// ---------------- sort-by-dst machinery ----------------

__global__ void hist_kernel(int* __restrict__ hist, const int* __restrict__ edst) {
  int i = blockIdx.x * blockDim.x + threadIdx.x;
  if (i < NBc * Ec) {
    int k = i / Ec;
    atomicAdd(&hist[k * Nc + edst[i]], 1);
  }
}

__global__ void scan_kernel(const int* __restrict__ hist, int* __restrict__ offs,
                            float* __restrict__ deginv) {
  const int k = blockIdx.x, tid = threadIdx.x;
  const int NPT = 40;
  __shared__ int part[256];
  int local[NPT];
  int sum = 0;
  for (int j = 0; j < NPT; ++j) {
    int n = tid * NPT + j;
    if (n < Nc) { local[j] = sum; sum += hist[k * Nc + n]; }
  }
  part[tid] = sum;
  __syncthreads();
  for (int off = 1; off < 256; off <<= 1) {
    int v = (tid >= off) ? part[tid - off] : 0;
    __syncthreads();
    part[tid] += v;
    __syncthreads();
  }
  int excl = part[tid] - sum;
  for (int j = 0; j < NPT; ++j) {
    int n = tid * NPT + j;
    if (n < Nc) {
      offs[k * Nc + n] = excl + local[j];
      deginv[k * Nc + n] = 1.f / fmaxf((float)hist[k * Nc + n], 1.f);
    }
  }
}

__global__ void sort_scatter_kernel(int* __restrict__ sorted, int* __restrict__ cursor,
                                    const int* __restrict__ offs, const int* __restrict__ edst) {
  int i = blockIdx.x * blockDim.x + threadIdx.x;
  if (i < NBc * Ec) {
    int k = i / Ec, e = i - k * Ec;
    int d = edst[i];
    int pos = offs[k * Nc + d] + atomicAdd(&cursor[k * Nc + d], 1);
    sorted[k * Ec + pos] = e;
  }
}

// ---------------- init kernels ----------------

__global__ void init_h_kernel(_Float16* __restrict__ h16, const float* __restrict__ bfeat,
                              const float* __restrict__ x, const float* __restrict__ Win,
                              const float* __restrict__ b_in, const int* __restrict__ ent) {
  int g = blockIdx.x * blockDim.x + threadIdx.x;
  if (g >= Bc * Nc * Hc) return;
  int j = g & (Hc - 1);
  int bn = g >> 7;
  int n = bn % Nc;
  int b = bn / Nc;
  float acc = b_in[j];
#pragma unroll
  for (int i = 0; i < DBc; ++i) acc = fmaf(bfeat[n * DBc + i], Win[i * Hc + j], acc);
  if (n == ent[b]) {
#pragma unroll
    for (int i = 0; i < DINc; ++i) acc = fmaf(x[b * DINc + i], Win[(DBc + i) * Hc + j], acc);
  }
  h16[g] = (_Float16)acc;
}

__global__ void init_p_kernel(float* __restrict__ p, const float* __restrict__ bp) {
  int i = blockIdx.x * blockDim.x + threadIdx.x;
  if (i < Bc * Nc * 3) p[i] = bp[i % (Nc * 3)];
}

// ---------------- weight -> extended f16 MFMA-fragment conversion ----------------
__global__ void conv_ext_kernel(_Float16* __restrict__ dst, const float* __restrict__ src,
                                const float* __restrict__ bias,
                                int nchunk, int total, int realRows, int biasRow) {
  int g = blockIdx.x * blockDim.x + threadIdx.x;
  if (g >= total) return;
  int j = g & 7;
  int lane = (g >> 3) & 63;
  int q = g >> 9;
  int t = q % nchunk;
  int q2 = q / nchunk;
  int wave = q2 & 3;
  int mat = q2 >> 2;
  int kk = t * 16 + (lane >> 5) * 8 + j;
  int col = (wave << 5) + (lane & 31);
  float v = 0.f;
  if (kk < realRows)      v = src[((size_t)mat * realRows + kk) * Hc + col];
  else if (kk == biasRow) v = bias[mat * Hc + col];
  dst[g] = (_Float16)v;
}

// ---------------- fused edge MLP kernel (TE=64, dual-accumulator) ----------------
// grid (B*E/64 = 3125, NB), 256 threads = 4 waves. 64 sorted edges/block in two
// halves (g=0: edges 0-31, g=1: 32-63). Each wave owns col-group wave*32; per
// weight chunk: ONE global load -> TWO independent MFMAs (halves weight L2
// traffic, guarantees MFMA ILP per load). Frag-order LDS throughout; scatter
// reads m2 directly from frag layout.

__global__ __launch_bounds__(256, 4)
void edge_mfma_kernel(const _Float16* __restrict__ h16, const float* __restrict__ p,
                      float* __restrict__ m_sum, float* __restrict__ p_new,
                      const float* __restrict__ deginv,
                      const int* __restrict__ esrc, const int* __restrict__ edst,
                      const int* __restrict__ sorted,
                      const _Float16* __restrict__ W1e, const _Float16* __restrict__ W2e,
                      const _Float16* __restrict__ P1e,
                      const float* __restrict__ pW2, const float* __restrict__ pb2,
                      int l) {
  const int k = blockIdx.y, lk = l * NBc + k;
  const int tid = threadIdx.x;
  const int wave = tid >> 6, lane = tid & 63;
  const int lrow = lane & 31, lhalf = lane >> 5;

  // RegA: 16 chunks x 2 edge-halves x 512 halfs = 32KB.
  // acts: hd chunks 0-7, hs chunks 8-15 -> m1 chunks 0-7 -> m2 chunks 8-15.
  __shared__ __align__(16) _Float16 RegA[16384];
  __shared__ __align__(16) _Float16 Dchk[1024];    // per-edge [d2,1,0..] K-ext chunk
  __shared__ int shd[64], shs[64], sOff[64];
  __shared__ float sdinv[64], srel[64][3], scoef[64];
  __shared__ float cpw2[Hc];
  __shared__ unsigned long long sflush;

  if (tid < Hc) cpw2[tid] = pW2[lk * Hc + tid];
  if (tid < 64) {
    int pos = blockIdx.x * 64 + tid;
    int b = (pos >= Ec) ? 1 : 0;
    int e = sorted[k * Ec + (pos - b * Ec)];
    int si = esrc[k * Ec + e], di = edst[k * Ec + e];
    int nd = b * Nc + di, ns = b * Nc + si;
    const float* pd = &p[(size_t)nd * 3];
    const float* ps = &p[(size_t)ns * 3];
    float rx = pd[0] - ps[0], ry = pd[1] - ps[1], rz = pd[2] - ps[2];
    srel[tid][0] = rx; srel[tid][1] = ry; srel[tid][2] = rz;
    float d2 = rx * rx + ry * ry + rz * rz;
    sdinv[tid] = deginv[k * Nc + di];
    shd[tid] = nd * Hc; shs[tid] = ns * Hc;
    sOff[tid] = nd * Hc;
    scoef[tid] = 0.f;
    h8 dv = (h8)(_Float16)0.f;
    h8 zv = (h8)(_Float16)0.f;
    dv[0] = (_Float16)d2; dv[1] = (_Float16)1.f;
    int g = tid >> 5, il = tid & 31;
    *(h8*)&Dchk[g * 512 + il * 8] = dv;          // khalf0 (k=0..7)
    *(h8*)&Dchk[g * 512 + 256 + il * 8] = zv;    // khalf1 (k=8..15)
    // segment boundaries (edges sorted by dst; batch boundary splits naturally)
    int prevn = __shfl_up(nd, 1);
    bool isStart = (tid == 0) || (nd != prevn);
    unsigned long long m = __ballot(isStart);
    if (tid == 0) sflush = (m >> 1) | (1ull << 63);
  }
  __syncthreads();

  // ---- gather h16 rows into frag order ----
  {
    const int i = tid & 63, cg = tid >> 6;     // edge i, col-group cg
    const int g = i >> 5, il = i & 31;
#pragma unroll
    for (int q = 0; q < 4; ++q) {
      int d0 = cg * 32 + q * 8;
      int t = d0 >> 4;
      int kh = q & 1;
      h8 vd = *(const h8*)&h16[shd[i] + d0];
      h8 vs = *(const h8*)&h16[shs[i] + d0];
      *(h8*)&RegA[(t * 2 + g) * 512 + kh * 256 + il * 8] = vd;
      *(h8*)&RegA[((8 + t) * 2 + g) * 512 + kh * 256 + il * 8] = vs;
    }
  }
  __syncthreads();

  // ---- GEMM1^T: K=272, dual edge-halves share each weight load ----
  const _Float16* wb1 = &W1e[(size_t)(lk * 4 + wave) * (17 * 512)];
  f32x16 aA, aB;
#pragma unroll
  for (int r = 0; r < 16; ++r) { aA[r] = 0.f; aB[r] = 0.f; }
#pragma unroll
  for (int t = 0; t < 16; ++t) {
    h8 aw = *(const h8*)&wb1[t * 512 + lane * 8];
    h8 bA = *(const h8*)&RegA[(t * 2 + 0) * 512 + lane * 8];
    h8 bB = *(const h8*)&RegA[(t * 2 + 1) * 512 + lane * 8];
    aA = __builtin_amdgcn_mfma_f32_32x32x16_f16(aw, bA, aA, 0, 0, 0);
    aB = __builtin_amdgcn_mfma_f32_32x32x16_f16(aw, bB, aB, 0, 0, 0);
  }
  {
    h8 aw = *(const h8*)&wb1[16 * 512 + lane * 8];
    h8 dA = *(const h8*)&Dchk[lane * 8];
    h8 dB = *(const h8*)&Dchk[512 + lane * 8];
    aA = __builtin_amdgcn_mfma_f32_32x32x16_f16(aw, dA, aA, 0, 0, 0);
    aB = __builtin_amdgcn_mfma_f32_32x32x16_f16(aw, dB, aB, 0, 0, 0);
  }
  h4 m1A[4], m1B[4];
#pragma unroll
  for (int c = 0; c < 4; ++c) {
    m1A[c] = pack4(silu_f(aA[c * 4 + 0]), silu_f(aA[c * 4 + 1]),
                   silu_f(aA[c * 4 + 2]), silu_f(aA[c * 4 + 3]));
    m1B[c] = pack4(silu_f(aB[c * 4 + 0]), silu_f(aB[c * 4 + 1]),
                   silu_f(aB[c * 4 + 2]), silu_f(aB[c * 4 + 3]));
  }
  __syncthreads();   // all GEMM1 act reads complete
#pragma unroll
  for (int c = 0; c < 4; ++c) {
    int t = 2 * wave + (c >> 1);
    int base = (c & 1) * 256 + lrow * 8 + lhalf * 4;
    *(h4*)&RegA[(t * 2 + 0) * 512 + base] = m1A[c];
    *(h4*)&RegA[(t * 2 + 1) * 512 + base] = m1B[c];
  }
  __syncthreads();

  // ---- GEMM2^T: K=144 ----
  const _Float16* wb2 = &W2e[(size_t)(lk * 4 + wave) * (9 * 512)];
#pragma unroll
  for (int r = 0; r < 16; ++r) { aA[r] = 0.f; aB[r] = 0.f; }
#pragma unroll
  for (int t = 0; t < 8; ++t) {
    h8 aw = *(const h8*)&wb2[t * 512 + lane * 8];
    h8 bA = *(const h8*)&RegA[(t * 2 + 0) * 512 + lane * 8];
    h8 bB = *(const h8*)&RegA[(t * 2 + 1) * 512 + lane * 8];
    aA = __builtin_amdgcn_mfma_f32_32x32x16_f16(aw, bA, aA, 0, 0, 0);
    aB = __builtin_amdgcn_mfma_f32_32x32x16_f16(aw, bB, aB, 0, 0, 0);
  }
  {
    h8 aw = *(const h8*)&wb2[8 * 512 + lane * 8];
    h8 dA = *(const h8*)&Dchk[lane * 8];
    h8 dB = *(const h8*)&Dchk[512 + lane * 8];
    aA = __builtin_amdgcn_mfma_f32_32x32x16_f16(aw, dA, aA, 0, 0, 0);
    aB = __builtin_amdgcn_mfma_f32_32x32x16_f16(aw, dB, aB, 0, 0, 0);
  }
  // m2 -> frag chunks 8-15 (hs region dead since GEMM1 barrier)
#pragma unroll
  for (int c = 0; c < 4; ++c) {
    h4 p2A = pack4(silu_f(aA[c * 4 + 0]), silu_f(aA[c * 4 + 1]),
                   silu_f(aA[c * 4 + 2]), silu_f(aA[c * 4 + 3]));
    h4 p2B = pack4(silu_f(aB[c * 4 + 0]), silu_f(aB[c * 4 + 1]),
                   silu_f(aB[c * 4 + 2]), silu_f(aB[c * 4 + 3]));
    int t2 = 8 + 2 * wave + (c >> 1);
    int base = (c & 1) * 256 + lrow * 8 + lhalf * 4;
    *(h4*)&RegA[(t2 * 2 + 0) * 512 + base] = p2A;
    *(h4*)&RegA[(t2 * 2 + 1) * 512 + base] = p2B;
  }
  __syncthreads();

  // ---- GEMM3^T: q = P1e([m2|1]); coef = sum silu(q)*pW2 ----
  const _Float16* wb3 = &P1e[(size_t)(lk * 4 + wave) * (9 * 512)];
#pragma unroll
  for (int r = 0; r < 16; ++r) { aA[r] = 0.f; aB[r] = 0.f; }
#pragma unroll
  for (int t = 0; t < 8; ++t) {
    h8 aw = *(const h8*)&wb3[t * 512 + lane * 8];
    h8 bA = *(const h8*)&RegA[((8 + t) * 2 + 0) * 512 + lane * 8];
    h8 bB = *(const h8*)&RegA[((8 + t) * 2 + 1) * 512 + lane * 8];
    aA = __builtin_amdgcn_mfma_f32_32x32x16_f16(aw, bA, aA, 0, 0, 0);
    aB = __builtin_amdgcn_mfma_f32_32x32x16_f16(aw, bB, aB, 0, 0, 0);
  }
  {
    h8 aw = *(const h8*)&wb3[8 * 512 + lane * 8];
    h8 dA = *(const h8*)&Dchk[lane * 8];
    h8 dB = *(const h8*)&Dchk[512 + lane * 8];
    aA = __builtin_amdgcn_mfma_f32_32x32x16_f16(aw, dA, aA, 0, 0, 0);
    aB = __builtin_amdgcn_mfma_f32_32x32x16_f16(aw, dB, aB, 0, 0, 0);
  }
  {
    float csA = 0.f, csB = 0.f;
#pragma unroll
    for (int r = 0; r < 16; ++r) {
      int hg = (wave << 5) + (r & 3) + ((r >> 2) << 3) + (lhalf << 2);
      csA += silu_f(aA[r]) * cpw2[hg];
      csB += silu_f(aB[r]) * cpw2[hg];
    }
    csA += __shfl_down(csA, 32);
    csB += __shfl_down(csB, 32);
    if (lane < 32) {
      atomicAdd(&scoef[lrow], csA);
      atomicAdd(&scoef[32 + lrow], csB);
    }
  }

  // ---- segmented m_sum scatter: read m2 directly from frag layout ----
  {
    const int col = tid & 127;
    const int half = tid >> 7;             // rows half*32 .. half*32+31
    const int base = ((8 + (col >> 4)) * 2 + half) * 512 + ((col >> 3) & 1) * 256 + (col & 7);
    const unsigned long long fm = sflush;
    float accv = 0.f;
#pragma unroll
    for (int rr = 0; rr < 32; ++rr) {
      int r = half * 32 + rr;
      accv += (float)RegA[base + rr * 8];
      if ((fm >> r) & 1ull) {
        atomicAdd(&m_sum[sOff[r] + col], accv * sdinv[r]);
        accv = 0.f;
      }
    }
    if (half == 0 && !((fm >> 31) & 1ull))
      atomicAdd(&m_sum[sOff[31] + col], accv * sdinv[31]);
  }
  __syncthreads();   // scoef complete
  // ---- p_new scatter ----
  if (tid < 64) {
    float cf = (scoef[tid] + pb2[lk]) * sdinv[tid];
    float* pp = &p_new[(size_t)(sOff[tid] / Hc) * 3];
    atomicAdd(&pp[0], srel[tid][0] * cf);
    atomicAdd(&pp[1], srel[tid][1] * cf);
    atomicAdd(&pp[2], srel[tid][2] * cf);
  }
}

// ---------------- node update kernel (TE=32 frag-order, unchanged) ----------------

__global__ __launch_bounds__(256, 8)
void update_mfma_kernel(_Float16* __restrict__ h16, const float* __restrict__ m_sum,
                        const _Float16* __restrict__ U1e, const _Float16* __restrict__ U2e,
                        int l) {
  const int tid = threadIdx.x;
  const int wave = tid >> 6, lane = tid & 63;
  const int lrow = lane & 31, lhalf = lane >> 5;
  const int row0 = blockIdx.x << 5;

  __shared__ __align__(16) _Float16 RegA[16 * 512];
  __shared__ __align__(16) _Float16 Dchk[512];

  if (tid < 64) {
    h8 dv = (h8)(_Float16)0.f;
    if (tid < 32) dv[1] = (_Float16)1.f;
    *(h8*)&Dchk[tid * 8] = dv;
  }
  {
    const int i = tid & 31, c = tid >> 5;
    size_t hb = (size_t)(row0 + i) * Hc;
    h8 v0 = *(const h8*)&h16[hb + c * 8];
    h8 v1 = *(const h8*)&h16[hb + 64 + c * 8];
    v4 m0 = *(const v4*)&m_sum[hb + c * 8];
    v4 m1 = *(const v4*)&m_sum[hb + c * 8 + 4];
    v4 m2 = *(const v4*)&m_sum[hb + 64 + c * 8];
    v4 m3 = *(const v4*)&m_sum[hb + 64 + c * 8 + 4];
    union { h8 v; h4 q[2]; } w0, w1;
    w0.q[0] = pack4(m0[0], m0[1], m0[2], m0[3]);
    w0.q[1] = pack4(m1[0], m1[1], m1[2], m1[3]);
    w1.q[0] = pack4(m2[0], m2[1], m2[2], m2[3]);
    w1.q[1] = pack4(m3[0], m3[1], m3[2], m3[3]);
    int slot = (i + ((c & 1) << 5)) << 3;
    int tb = (c >> 1) << 9;
    *(h8*)&RegA[tb + slot] = v0;
    *(h8*)&RegA[tb + 4 * 512 + slot] = v1;
    *(h8*)&RegA[tb + 8 * 512 + slot] = w0.v;
    *(h8*)&RegA[tb + 12 * 512 + slot] = w1.v;
  }
  __syncthreads();

  const _Float16* wb1 = &U1e[(size_t)(l * 4 + wave) * (17 * 512)];
  f32x16 acc;
#pragma unroll
  for (int r = 0; r < 16; ++r) acc[r] = 0.f;
#pragma unroll
  for (int t = 0; t < 16; ++t) {
    h8 bact = *(const h8*)&RegA[t * 512 + lane * 8];
    h8 aw   = *(const h8*)&wb1[t * 512 + lane * 8];
    acc = __builtin_amdgcn_mfma_f32_32x32x16_f16(aw, bact, acc, 0, 0, 0);
  }
  {
    h8 bact = *(const h8*)&Dchk[lane * 8];
    h8 aw   = *(const h8*)&wb1[16 * 512 + lane * 8];
    acc = __builtin_amdgcn_mfma_f32_32x32x16_f16(aw, bact, acc, 0, 0, 0);
  }
  h4 u1pk[4];
#pragma unroll
  for (int c = 0; c < 4; ++c)
    u1pk[c] = pack4(silu_f(acc[c * 4 + 0]), silu_f(acc[c * 4 + 1]),
                    silu_f(acc[c * 4 + 2]), silu_f(acc[c * 4 + 3]));
  __syncthreads();
#pragma unroll
  for (int c = 0; c < 4; ++c) {
    int t = (wave << 1) + (c >> 1);
    int slot = lrow + ((c & 1) << 5);
    *(h4*)&RegA[t * 512 + slot * 8 + lhalf * 4] = u1pk[c];
  }
  __syncthreads();

  const _Float16* wb2 = &U2e[(size_t)(l * 4 + wave) * (9 * 512)];
  f32x16 acc2;
#pragma unroll
  for (int r = 0; r < 16; ++r) acc2[r] = 0.f;
#pragma unroll
  for (int t = 0; t < 8; ++t) {
    h8 bact = *(const h8*)&RegA[t * 512 + lane * 8];
    h8 aw   = *(const h8*)&wb2[t * 512 + lane * 8];
    acc2 = __builtin_amdgcn_mfma_f32_32x32x16_f16(aw, bact, acc2, 0, 0, 0);
  }
  {
    h8 bact = *(const h8*)&Dchk[lane * 8];
    h8 aw   = *(const h8*)&wb2[8 * 512 + lane * 8];
    acc2 = __builtin_amdgcn_mfma_f32_32x32x16_f16(aw, bact, acc2, 0, 0, 0);
  }
  {
    _Float16* hp = &h16[(size_t)(row0 + lrow) * Hc];
#pragma unroll
    for (int c = 0; c < 4; ++c) {
      int hb = (wave << 5) + (c << 3) + (lhalf << 2);
      h4 old = *(const h4*)&hp[hb];
      *(h4*)&hp[hb] = pack4((float)old[0] + acc2[c * 4 + 0], (float)old[1] + acc2[c * 4 + 1],
                            (float)old[2] + acc2[c * 4 + 2], (float)old[3] + acc2[c * 4 + 3]);
    }
  }
}

// ---------------- readout ----------------

__global__ void readout_kernel(const _Float16* __restrict__ h16, const int* __restrict__ ent,
                               const float* __restrict__ oW1, const float* __restrict__ ob1,
                               const float* __restrict__ oW2, const float* __restrict__ ob2,
                               float* __restrict__ out) {
  __shared__ float tb[Bc][Hc];
  int tid = threadIdx.x;
  int b = tid >> 7, j = tid & 127;
  const _Float16* e = &h16[((size_t)(b * Nc + ent[b])) * Hc];
  float a = ob1[j];
#pragma unroll 4
  for (int i = 0; i < Hc; ++i) a = fmaf((float)e[i], oW1[i * Hc + j], a);
  tb[b][j] = silu_f(a);
  __syncthreads();
  if (tid < Bc) {
    float s = ob2[0];
    for (int i = 0; i < Hc; ++i) s = fmaf(tb[tid][i], oW2[i], s);
    out[tid] = s;
  }
}

// ---------------- host launcher ----------------

extern "C" void kernel_launch(void* const* d_in, const int* in_sizes, int n_in,
                              void* d_out, int out_size, void* d_ws, size_t ws_size,
                              hipStream_t stream) {
  const float* x    = (const float*)d_in[0];
  const float* bfe  = (const float*)d_in[1];
  const float* bp   = (const float*)d_in[2];
  const float* Win  = (const float*)d_in[3];
  const float* b_in = (const float*)d_in[4];
  const float* mW1  = (const float*)d_in[5];
  const float* mb1  = (const float*)d_in[6];
  const float* mW2  = (const float*)d_in[7];
  const float* mb2  = (const float*)d_in[8];
  const float* pW1  = (const float*)d_in[9];
  const float* pb1  = (const float*)d_in[10];
  const float* pW2  = (const float*)d_in[11];
  const float* pb2  = (const float*)d_in[12];
  const float* uW1  = (const float*)d_in[13];
  const float* ub1  = (const float*)d_in[14];
  const float* uW2  = (const float*)d_in[15];
  const float* ub2  = (const float*)d_in[16];
  const float* oW1  = (const float*)d_in[17];
  const float* ob1  = (const float*)d_in[18];
  const float* oW2  = (const float*)d_in[19];
  const float* ob2  = (const float*)d_in[20];
  const int* ent    = (const int*)d_in[21];
  const int* esrc   = (const int*)d_in[22];
  const int* edst   = (const int*)d_in[23];

  float* wsf = (float*)d_ws;
  float* msum   = wsf;  wsf += (size_t)Bc * Nc * Hc;
  float* pa     = wsf;  wsf += (size_t)Bc * Nc * 3;
  float* pb_    = wsf;  wsf += (size_t)Bc * Nc * 3;
  float* deginv = wsf;  wsf += (size_t)NBc * Nc;
  _Float16* h16 = (_Float16*)wsf;
  _Float16* W1e = h16 + (size_t)Bc * Nc * Hc;
  _Float16* W2e = W1e + 208896;   // 6*4*17*512
  _Float16* P1e = W2e + 110592;   // 6*4*9*512
  _Float16* U1e = P1e + 110592;
  _Float16* U2e = U1e + 69632;    // 2*4*17*512
  int* hist   = (int*)(U2e + 36864);
  int* cursor = hist + NBc * Nc;
  int* offs   = cursor + NBc * Nc;
  int* sorted = offs + NBc * Nc;

  // --- sort edges by dst (once per call; hist doubles as degree) ---
  zero4_kernel<<<dim3((2 * NBc * Nc / 4 + 255) / 256), dim3(256), 0, stream>>>((float*)hist, 2 * NBc * Nc / 4);
  hist_kernel<<<dim3((NBc * Ec + 255) / 256), dim3(256), 0, stream>>>(hist, edst);
  scan_kernel<<<dim3(NBc), dim3(256), 0, stream>>>(hist, offs, deginv);
  sort_scatter_kernel<<<dim3((NBc * Ec + 255) / 256), dim3(256), 0, stream>>>(sorted, cursor, offs, edst);

  // --- extended weight fragment conversions (bias/d2 rows folded) ---
  conv_ext_kernel<<<dim3(816), dim3(256), 0, stream>>>(W1e, mW1, mb1, 17, 208896, 257, 257);
  conv_ext_kernel<<<dim3(432), dim3(256), 0, stream>>>(W2e, mW2, mb2, 9, 110592, 128, 129);
  conv_ext_kernel<<<dim3(432), dim3(256), 0, stream>>>(P1e, pW1, pb1, 9, 110592, 128, 129);
  conv_ext_kernel<<<dim3(272), dim3(256), 0, stream>>>(U1e, uW1, ub1, 17, 69632, 256, 257);
  conv_ext_kernel<<<dim3(144), dim3(256), 0, stream>>>(U2e, uW2, ub2, 9, 36864, 128, 129);

  init_h_kernel<<<dim3((Bc * Nc * Hc + 255) / 256), dim3(256), 0, stream>>>(h16, bfe, x, Win, b_in, ent);
  init_p_kernel<<<dim3((Bc * Nc * 3 + 255) / 256), dim3(256), 0, stream>>>(pa, bp);

  float* pcur = pa;
  float* pnew = pb_;
  const int nmh = Bc * Nc * Hc;
  for (int l = 0; l < Lc; ++l) {
    zero4_kernel<<<dim3((nmh / 4 + 255) / 256), dim3(256), 0, stream>>>(msum, nmh / 4);
    copy_kernel<<<dim3((Bc * Nc * 3 + 255) / 256), dim3(256), 0, stream>>>(pnew, pcur, Bc * Nc * 3);
    edge_mfma_kernel<<<dim3(Bc * Ec / 64, NBc), dim3(256), 0, stream>>>(
        h16, pcur, msum, pnew, deginv, esrc, edst, sorted,
        W1e, W2e, P1e, pW2, pb2, l);
    update_mfma_kernel<<<dim3(Bc * Nc / 32), dim3(256), 0, stream>>>(h16, msum, U1e, U2e, l);
    float* t = pcur; pcur = pnew; pnew = t;
  }
  readout_kernel<<<dim3(1), dim3(256), 0, stream>>>(h16, ent, oW1, ob1, oW2, ob2, (float*)d_out);
}